// Round 1
// baseline (646.022 us; speedup 1.0000x reference)
//
#include <hip/hip_runtime.h>

#define NN 50000      // nodes
#define NE 800000     // edges
#define NB 128        // graphs / batch
#define SD 64         // state dim / node dim
#define GH 128        // gnn layer1 width
#define GD 64         // gnn layer2 width
#define HID 256       // actor hidden
#define AD 8          // action dim

static inline size_t align256(size_t x){ return (x + 255) & ~size_t(255); }

// ---------------- CSR build ----------------
__global__ void k_hist(const int* __restrict__ dst, int* __restrict__ cnt){
  int e = blockIdx.x*256 + threadIdx.x;
  if (e < NE) atomicAdd(&cnt[dst[e]], 1);
}

__global__ void k_scan(const int* __restrict__ cnt, int* __restrict__ offs,
                       int* __restrict__ cursor){
  __shared__ int part[1024];
  int t = threadIdx.x;
  const int chunk = (NN + 1023)/1024;
  int lo = t*chunk; int hi = lo + chunk; if (hi > NN) hi = NN;
  int s = 0;
  for (int i = lo; i < hi; ++i) s += cnt[i];
  part[t] = s;
  __syncthreads();
  for (int d = 1; d < 1024; d <<= 1){
    int v = (t >= d) ? part[t-d] : 0;
    __syncthreads();
    part[t] += v;
    __syncthreads();
  }
  int run = part[t] - s;  // exclusive prefix of this chunk
  for (int i = lo; i < hi; ++i){ offs[i] = run; cursor[i] = run; run += cnt[i]; }
}

__global__ void k_scatter(const int* __restrict__ esrc, const int* __restrict__ edst,
                          int* __restrict__ cursor, int* __restrict__ ssrc){
  int e = blockIdx.x*256 + threadIdx.x;
  if (e < NE){
    int p = atomicAdd(&cursor[edst[e]], 1);
    ssrc[p] = esrc[e];
  }
}

// ---------------- fp32 tiled GEMM: Out[M,64*gridDim.y] = post(In[M,K] @ W[K, ldw]) --------
// Epilogue: if cnt: v = (v + cnt[m]*bias[j]) / max(cnt[m],1); if relu: max(v,0)
__global__ __launch_bounds__(256)
void k_gemm(const float* __restrict__ In, const float* __restrict__ W,
            float* __restrict__ Out, int M, int K, int ldw, int ldo,
            const int* __restrict__ cnt, const float* __restrict__ bias, int do_relu)
{
  __shared__ float As[16][68];   // [k][row-in-tile], stride 68 keeps float4 16B-aligned
  __shared__ float Ws[16][64];   // [k][col-in-tile]
  int tid = threadIdx.x;
  int tx = tid & 15, ty = tid >> 4;
  int m0 = blockIdx.x * 64, n0 = blockIdx.y * 64;
  float acc[4][4];
  #pragma unroll
  for (int r = 0; r < 4; ++r)
    #pragma unroll
    for (int c = 0; c < 4; ++c) acc[r][c] = 0.f;

  for (int k0 = 0; k0 < K; k0 += 16){
    #pragma unroll
    for (int i = 0; i < 4; ++i){
      int e = tid + i*256;
      int r = e >> 4, c = e & 15;
      int m = m0 + r;
      As[c][r] = (m < M) ? In[(size_t)m*K + k0 + c] : 0.f;
      int wr = e >> 6, wc = e & 63;
      Ws[wr][wc] = W[(size_t)(k0 + wr)*ldw + n0 + wc];
    }
    __syncthreads();
    #pragma unroll
    for (int kk = 0; kk < 16; ++kk){
      float4 a = *reinterpret_cast<const float4*>(&As[kk][ty*4]);
      float4 w = *reinterpret_cast<const float4*>(&Ws[kk][tx*4]);
      acc[0][0] = fmaf(a.x, w.x, acc[0][0]);
      acc[0][1] = fmaf(a.x, w.y, acc[0][1]);
      acc[0][2] = fmaf(a.x, w.z, acc[0][2]);
      acc[0][3] = fmaf(a.x, w.w, acc[0][3]);
      acc[1][0] = fmaf(a.y, w.x, acc[1][0]);
      acc[1][1] = fmaf(a.y, w.y, acc[1][1]);
      acc[1][2] = fmaf(a.y, w.z, acc[1][2]);
      acc[1][3] = fmaf(a.y, w.w, acc[1][3]);
      acc[2][0] = fmaf(a.z, w.x, acc[2][0]);
      acc[2][1] = fmaf(a.z, w.y, acc[2][1]);
      acc[2][2] = fmaf(a.z, w.z, acc[2][2]);
      acc[2][3] = fmaf(a.z, w.w, acc[2][3]);
      acc[3][0] = fmaf(a.w, w.x, acc[3][0]);
      acc[3][1] = fmaf(a.w, w.y, acc[3][1]);
      acc[3][2] = fmaf(a.w, w.z, acc[3][2]);
      acc[3][3] = fmaf(a.w, w.w, acc[3][3]);
    }
    __syncthreads();
  }
  #pragma unroll
  for (int r = 0; r < 4; ++r){
    int m = m0 + ty*4 + r;
    if (m >= M) continue;
    float fcnt = 0.f, inv = 1.f;
    if (cnt){ fcnt = (float)cnt[m]; inv = 1.f / fmaxf(fcnt, 1.f); }
    float4 o;
    #pragma unroll
    for (int c = 0; c < 4; ++c){
      float v = acc[r][c];
      if (cnt) v = (v + fcnt * bias[n0 + tx*4 + c]) * inv;
      if (do_relu) v = fmaxf(v, 0.f);
      (&o.x)[c] = v;
    }
    *reinterpret_cast<float4*>(&Out[(size_t)m*ldo + n0 + tx*4]) = o;
  }
}

// ---------------- edge aggregation, layer 1 (dim 128, 2 ch/lane) ----------------
__global__ __launch_bounds__(64)
void k_edge1(const float* __restrict__ A, const float* __restrict__ Bm,
             const float* __restrict__ b1, const int* __restrict__ offs,
             const int* __restrict__ cnt, const int* __restrict__ ssrc,
             float* __restrict__ S)
{
  int v = blockIdx.x;
  int c = threadIdx.x;  // 0..63 -> channels 2c, 2c+1
  float2 a  = *reinterpret_cast<const float2*>(&A[(size_t)v*GH + 2*c]);
  float2 bb = *reinterpret_cast<const float2*>(&b1[2*c]);
  float ax = a.x + bb.x, ay = a.y + bb.y;
  int beg = offs[v], n = cnt[v];
  float sx = 0.f, sy = 0.f;
  int snext = (n > 0) ? ssrc[beg] : 0;
  for (int i = 0; i < n; ++i){
    int s = snext;
    if (i + 1 < n) snext = ssrc[beg + i + 1];
    float2 bv = *reinterpret_cast<const float2*>(&Bm[(size_t)s*GH + 2*c]);
    sx += fmaxf(ax + bv.x, 0.f);
    sy += fmaxf(ay + bv.y, 0.f);
  }
  *reinterpret_cast<float2*>(&S[(size_t)v*GH + 2*c]) = make_float2(sx, sy);
}

// ---------------- edge aggregation, layer 2 (dim 64, 1 ch/lane) ----------------
__global__ __launch_bounds__(64)
void k_edge2(const float* __restrict__ C, const float* __restrict__ D,
             const float* __restrict__ b1, const int* __restrict__ offs,
             const int* __restrict__ cnt, const int* __restrict__ ssrc,
             float* __restrict__ S2)
{
  int v = blockIdx.x;
  int c = threadIdx.x;
  float a = C[(size_t)v*GD + c] + b1[c];
  int beg = offs[v], n = cnt[v];
  float s = 0.f;
  int snext = (n > 0) ? ssrc[beg] : 0;
  for (int i = 0; i < n; ++i){
    int u = snext;
    if (i + 1 < n) snext = ssrc[beg + i + 1];
    s += fmaxf(a + D[(size_t)u*GD + c], 0.f);
  }
  S2[(size_t)v*GD + c] = s;
}

// ---------------- graph scatter-mean (node_batch sorted -> binary search) ------
__global__ __launch_bounds__(64)
void k_graph(const float* __restrict__ H2, const int* __restrict__ nb,
             float* __restrict__ embed)
{
  __shared__ int bounds[2];
  int b = blockIdx.x, c = threadIdx.x;
  if (c < 2){
    int target = b + c;
    int lo = 0, hi = NN;
    while (lo < hi){ int mid = (lo + hi) >> 1; if (nb[mid] < target) lo = mid + 1; else hi = mid; }
    bounds[c] = lo;
  }
  __syncthreads();
  int lo = bounds[0], hi = bounds[1];
  float s = 0.f;
  for (int n = lo; n < hi; ++n) s += H2[(size_t)n*GD + c];
  embed[b*GD + c] = s / fmaxf((float)(hi - lo), 1.f);
}

// ---------------- actor head: one block per batch row ----------------
__global__ __launch_bounds__(256)
void k_head(const float* __restrict__ state, const float* __restrict__ embed,
            const float* __restrict__ fc1w, const float* __restrict__ fc1b,
            const float* __restrict__ fc2w, const float* __restrict__ fc2b,
            const float* __restrict__ mw, const float* __restrict__ mb,
            const float* __restrict__ lw, const float* __restrict__ lb,
            float* __restrict__ out)
{
  int b = blockIdx.x, t = threadIdx.x;
  __shared__ float z[SD + GD];
  __shared__ float h1[HID];
  __shared__ float h2[HID];
  if (t < SD) z[t] = state[b*SD + t];
  else if (t < SD + GD) z[t] = embed[b*GD + (t - SD)];
  __syncthreads();
  float acc = fc1b[t];
  for (int k = 0; k < SD + GD; ++k) acc = fmaf(z[k], fc1w[k*HID + t], acc);
  h1[t] = fmaxf(acc, 0.f);
  __syncthreads();
  acc = fc2b[t];
  for (int k = 0; k < HID; ++k) acc = fmaf(h1[k], fc2w[k*HID + t], acc);
  h2[t] = fmaxf(acc, 0.f);
  __syncthreads();
  if (t < AD){
    float m = mb[t];
    for (int k = 0; k < HID; ++k) m = fmaf(h2[k], mw[k*AD + t], m);
    out[b*AD + t] = m;
  } else if (t < 2*AD){
    int j = t - AD;
    float l = lb[j];
    for (int k = 0; k < HID; ++k) l = fmaf(h2[k], lw[k*AD + j], l);
    out[NB*AD + b*AD + j] = fminf(fmaxf(l, -20.f), 2.f);
  }
}

extern "C" void kernel_launch(void* const* d_in, const int* in_sizes, int n_in,
                              void* d_out, int out_size, void* d_ws, size_t ws_size,
                              hipStream_t stream)
{
  const float* state = (const float*)d_in[0];
  const float* x     = (const float*)d_in[1];
  const int*   eidx  = (const int*)  d_in[2];
  const int*   nb    = (const int*)  d_in[3];
  const float* g1w1  = (const float*)d_in[4];
  const float* g1b1  = (const float*)d_in[5];
  const float* g1w2  = (const float*)d_in[6];
  const float* g1b2  = (const float*)d_in[7];
  const float* g2w1  = (const float*)d_in[8];
  const float* g2b1  = (const float*)d_in[9];
  const float* g2w2  = (const float*)d_in[10];
  const float* g2b2  = (const float*)d_in[11];
  const float* fc1w  = (const float*)d_in[12];
  const float* fc1b  = (const float*)d_in[13];
  const float* fc2w  = (const float*)d_in[14];
  const float* fc2b  = (const float*)d_in[15];
  const float* mw    = (const float*)d_in[16];
  const float* mb    = (const float*)d_in[17];
  const float* lw    = (const float*)d_in[18];
  const float* lb    = (const float*)d_in[19];

  const int* e_src = eidx;        // edge_index[0]
  const int* e_dst = eidx + NE;   // edge_index[1]

  char* p = (char*)d_ws;
  auto alloc = [&](size_t bytes){ char* r = p; p += align256(bytes); return r; };
  int*   cnt    = (int*)  alloc((size_t)NN*4);
  int*   offs   = (int*)  alloc((size_t)NN*4);
  int*   cursor = (int*)  alloc((size_t)NN*4);
  int*   ssrc   = (int*)  alloc((size_t)NE*4);
  float* fA     = (float*)alloc((size_t)NN*GH*4);
  float* fB     = (float*)alloc((size_t)NN*GH*4);
  float* fS     = (float*)alloc((size_t)NN*GH*4);
  float* fH     = (float*)alloc((size_t)NN*GH*4);
  // overlays (lifetimes disjoint):
  float* fC     = fA;                      // [NN,64]
  float* fD     = fA + (size_t)NN*GD;      // [NN,64]
  float* fS2    = fB;                      // [NN,64]
  float* fH2    = fB + (size_t)NN*GD;      // [NN,64]
  float* embed  = fS;                      // [NB,64]

  hipMemsetAsync(cnt, 0, (size_t)NN*4, stream);

  dim3 b256(256), b64(64), b1024(1024);
  k_hist   <<<dim3((NE+255)/256), b256, 0, stream>>>(e_dst, cnt);
  k_scan   <<<dim3(1), b1024, 0, stream>>>(cnt, offs, cursor);
  k_scatter<<<dim3((NE+255)/256), b256, 0, stream>>>(e_src, e_dst, cursor, ssrc);

  const int MB = (NN + 63)/64;  // 782
  // Layer 1: A = x @ w1[0:64,:], B = x @ w1[64:128,:]
  k_gemm<<<dim3(MB,2), b256, 0, stream>>>(x, g1w1,          fA, NN, 64, GH, GH, nullptr, nullptr, 0);
  k_gemm<<<dim3(MB,2), b256, 0, stream>>>(x, g1w1 + 64*GH,  fB, NN, 64, GH, GH, nullptr, nullptr, 0);
  k_edge1<<<dim3(NN), b64, 0, stream>>>(fA, fB, g1b1, offs, cnt, ssrc, fS);
  // h = relu((S @ w2 + cnt*b2)/max(cnt,1))
  k_gemm<<<dim3(MB,2), b256, 0, stream>>>(fS, g1w2, fH, NN, 128, GH, GH, cnt, g1b2, 1);

  // Layer 2: C = h @ w1[0:128,:], D = h @ w1[128:256,:]
  k_gemm<<<dim3(MB,1), b256, 0, stream>>>(fH, g2w1,            fC, NN, 128, GD, GD, nullptr, nullptr, 0);
  k_gemm<<<dim3(MB,1), b256, 0, stream>>>(fH, g2w1 + 128*GD,   fD, NN, 128, GD, GD, nullptr, nullptr, 0);
  k_edge2<<<dim3(NN), b64, 0, stream>>>(fC, fD, g2b1, offs, cnt, ssrc, fS2);
  // h2 = (S2 @ w2 + cnt*b2)/max(cnt,1)   (no relu)
  k_gemm<<<dim3(MB,1), b256, 0, stream>>>(fS2, g2w2, fH2, NN, 64, GD, GD, cnt, g2b2, 0);

  k_graph<<<dim3(NB), b64, 0, stream>>>(fH2, nb, embed);
  k_head <<<dim3(NB), b256, 0, stream>>>(state, embed, fc1w, fc1b, fc2w, fc2b,
                                         mw, mb, lw, lb, (float*)d_out);
}

// Round 2
// 538.850 us; speedup vs baseline: 1.1989x; 1.1989x over previous
//
#include <hip/hip_runtime.h>

#define NN 50000      // nodes
#define NE 800000     // edges
#define NB 128        // graphs / batch
#define SD 64         // state dim / node dim
#define GH 128        // gnn layer1 width
#define GD 64         // gnn layer2 width
#define HID 256       // actor hidden
#define AD 8          // action dim
#define SCB 196       // scan blocks: 196*256 = 50176 >= NN

static inline size_t align256(size_t x){ return (x + 255) & ~size_t(255); }

typedef __attribute__((ext_vector_type(8))) short short8v;
typedef __attribute__((ext_vector_type(4))) float f32x4;

// Split fp32 into hi/lo bf16 (truncation; lo captures the tail exactly enough:
// combined representation error ~2^-16 relative).
__device__ inline void bsplit(float f, short& h, short& l){
  unsigned u = __builtin_bit_cast(unsigned, f);
  h = (short)(u >> 16);
  float hif = __builtin_bit_cast(float, u & 0xFFFF0000u);
  float rem = f - hif;   // exact
  l = (short)(__builtin_bit_cast(unsigned, rem) >> 16);
}

// ---------------- CSR build ----------------
__global__ void k_hist(const int* __restrict__ dst, int* __restrict__ cnt){
  int e = blockIdx.x*256 + threadIdx.x;
  if (e < NE) atomicAdd(&cnt[dst[e]], 1);
}

__global__ __launch_bounds__(256)
void k_scan_a(const int* __restrict__ cnt, int* __restrict__ bsum){
  __shared__ int sm[256];
  int t = threadIdx.x;
  int i = blockIdx.x*256 + t;
  int v = (i < NN) ? cnt[i] : 0;
  sm[t] = v; __syncthreads();
  for (int d = 128; d > 0; d >>= 1){
    if (t < d) sm[t] += sm[t + d];
    __syncthreads();
  }
  if (t == 0) bsum[blockIdx.x] = sm[0];
}

__global__ __launch_bounds__(256)
void k_scan_b(const int* __restrict__ bsum, int* __restrict__ boff){
  __shared__ int sm[256];
  int t = threadIdx.x;
  int v = (t < SCB) ? bsum[t] : 0;
  sm[t] = v; __syncthreads();
  for (int d = 1; d < 256; d <<= 1){
    int add = (t >= d) ? sm[t - d] : 0;
    __syncthreads();
    sm[t] += add;
    __syncthreads();
  }
  if (t < SCB) boff[t] = sm[t] - v;   // exclusive
}

__global__ __launch_bounds__(256)
void k_scan_c(const int* __restrict__ cnt, const int* __restrict__ boff,
              int* __restrict__ offs, int* __restrict__ cursor){
  __shared__ int sm[256];
  int t = threadIdx.x;
  int i = blockIdx.x*256 + t;
  int v = (i < NN) ? cnt[i] : 0;
  sm[t] = v; __syncthreads();
  for (int d = 1; d < 256; d <<= 1){
    int add = (t >= d) ? sm[t - d] : 0;
    __syncthreads();
    sm[t] += add;
    __syncthreads();
  }
  if (i < NN){
    int e = sm[t] - v + boff[blockIdx.x];
    offs[i] = e; cursor[i] = e;
  }
}

__global__ void k_scatter(const int* __restrict__ esrc, const int* __restrict__ edst,
                          int* __restrict__ cursor, int* __restrict__ ssrc){
  int e = blockIdx.x*256 + threadIdx.x;
  if (e < NE){
    int p = atomicAdd(&cursor[edst[e]], 1);
    ssrc[p] = esrc[e];
  }
}

// ---------------- split-bf16 MFMA GEMM ----------------
// Out[M, 64*gridDim.y] = post(In[M,K] @ W[K,ldw] cols [n0,n0+64))
// post: if cnt: v=(v+cnt[m]*bias[n])/max(cnt[m],1); if relu: max(v,0)
// Block: 256 thr (4 waves), tile 64x64, MFMA 16x16x32_bf16, 3-pass hi/lo.
__global__ __launch_bounds__(256)
void k_mgemm(const float* __restrict__ In, const float* __restrict__ W,
             float* __restrict__ Out, int M, int K, int ldw, int ldo,
             const int* __restrict__ cnt, const float* __restrict__ bias,
             int do_relu)
{
  // row stride 40 shorts (80 B = 5 banks*16B) -> 2-way max conflict on b128 reads
  __shared__ short Ah[64*40], Al[64*40], Bh[64*40], Bl[64*40];
  int tid = threadIdx.x;
  int w = tid >> 6, lane = tid & 63, l15 = tid & 15, quad = lane >> 4;
  int m0 = blockIdx.x*64, n0 = blockIdx.y*64;
  f32x4 acc[4];
  #pragma unroll
  for (int t = 0; t < 4; ++t) acc[t] = (f32x4){0.f,0.f,0.f,0.f};

  for (int k0 = 0; k0 < K; k0 += 32){
    // stage A tile [64 rows x 32 k] as hi/lo bf16, layout [m][k]
    #pragma unroll
    for (int i = 0; i < 2; ++i){
      int s = tid + i*256;        // 0..511 float4 slots
      int m = s >> 3, q = s & 7;  // row, k-quad
      float4 v = make_float4(0.f,0.f,0.f,0.f);
      if (m0 + m < M) v = *reinterpret_cast<const float4*>(&In[(size_t)(m0+m)*K + k0 + q*4]);
      short4 h4, l4;
      bsplit(v.x, h4.x, l4.x); bsplit(v.y, h4.y, l4.y);
      bsplit(v.z, h4.z, l4.z); bsplit(v.w, h4.w, l4.w);
      *reinterpret_cast<short4*>(&Ah[m*40 + q*4]) = h4;
      *reinterpret_cast<short4*>(&Al[m*40 + q*4]) = l4;
    }
    // stage B tile [32 k x 64 n] transposed to [n][k]
    #pragma unroll
    for (int i = 0; i < 2; ++i){
      int s = tid + i*256;          // 0..511
      int r = s >> 4, cq = s & 15;  // k-row, col-quad
      float4 v = *reinterpret_cast<const float4*>(&W[(size_t)(k0+r)*ldw + n0 + cq*4]);
      #pragma unroll
      for (int j = 0; j < 4; ++j){
        short h, l; bsplit((&v.x)[j], h, l);
        Bh[(cq*4+j)*40 + r] = h;
        Bl[(cq*4+j)*40 + r] = l;
      }
    }
    __syncthreads();
    short8v ah = *reinterpret_cast<short8v*>(&Ah[(w*16 + l15)*40 + quad*8]);
    short8v al = *reinterpret_cast<short8v*>(&Al[(w*16 + l15)*40 + quad*8]);
    #pragma unroll
    for (int t = 0; t < 4; ++t){
      short8v bh = *reinterpret_cast<short8v*>(&Bh[(t*16 + l15)*40 + quad*8]);
      short8v bl = *reinterpret_cast<short8v*>(&Bl[(t*16 + l15)*40 + quad*8]);
      acc[t] = __builtin_amdgcn_mfma_f32_16x16x32_bf16(ah, bh, acc[t], 0, 0, 0);
      acc[t] = __builtin_amdgcn_mfma_f32_16x16x32_bf16(ah, bl, acc[t], 0, 0, 0);
      acc[t] = __builtin_amdgcn_mfma_f32_16x16x32_bf16(al, bh, acc[t], 0, 0, 0);
    }
    __syncthreads();
  }
  #pragma unroll
  for (int r = 0; r < 4; ++r){
    int m = m0 + w*16 + quad*4 + r;   // C/D row = quad*4 + reg
    if (m >= M) continue;
    float fcnt = 0.f, inv = 1.f;
    if (cnt){ fcnt = (float)cnt[m]; inv = 1.f / fmaxf(fcnt, 1.f); }
    #pragma unroll
    for (int t = 0; t < 4; ++t){
      int n = n0 + t*16 + l15;        // C/D col = lane&15
      float v = acc[t][r];
      if (cnt) v = (v + fcnt * bias[n]) * inv;
      if (do_relu) v = fmaxf(v, 0.f);
      Out[(size_t)m*ldo + n] = v;
    }
  }
}

// ---------------- edge aggregation, layer 1 (dim 128, 2 ch/lane) ----------------
__global__ __launch_bounds__(64)
void k_edge1(const float* __restrict__ A, const float* __restrict__ Bm,
             const float* __restrict__ b1, const int* __restrict__ offs,
             const int* __restrict__ cnt, const int* __restrict__ ssrc,
             float* __restrict__ S)
{
  int v = blockIdx.x;
  int c = threadIdx.x;  // 0..63 -> channels 2c, 2c+1
  float2 a  = *reinterpret_cast<const float2*>(&A[(size_t)v*GH + 2*c]);
  float2 bb = *reinterpret_cast<const float2*>(&b1[2*c]);
  float ax = a.x + bb.x, ay = a.y + bb.y;
  int beg = offs[v], n = cnt[v];
  float sx = 0.f, sy = 0.f;
  int snext = (n > 0) ? ssrc[beg] : 0;
  for (int i = 0; i < n; ++i){
    int s = snext;
    if (i + 1 < n) snext = ssrc[beg + i + 1];
    float2 bv = *reinterpret_cast<const float2*>(&Bm[(size_t)s*GH + 2*c]);
    sx += fmaxf(ax + bv.x, 0.f);
    sy += fmaxf(ay + bv.y, 0.f);
  }
  *reinterpret_cast<float2*>(&S[(size_t)v*GH + 2*c]) = make_float2(sx, sy);
}

// ---------------- edge aggregation, layer 2 (dim 64, 1 ch/lane) ----------------
__global__ __launch_bounds__(64)
void k_edge2(const float* __restrict__ C, const float* __restrict__ D,
             const float* __restrict__ b1, const int* __restrict__ offs,
             const int* __restrict__ cnt, const int* __restrict__ ssrc,
             float* __restrict__ S2)
{
  int v = blockIdx.x;
  int c = threadIdx.x;
  float a = C[(size_t)v*GD + c] + b1[c];
  int beg = offs[v], n = cnt[v];
  float s = 0.f;
  int snext = (n > 0) ? ssrc[beg] : 0;
  for (int i = 0; i < n; ++i){
    int u = snext;
    if (i + 1 < n) snext = ssrc[beg + i + 1];
    s += fmaxf(a + D[(size_t)u*GD + c], 0.f);
  }
  S2[(size_t)v*GD + c] = s;
}

// ---------------- graph scatter-mean (node_batch sorted -> binary search) ------
__global__ __launch_bounds__(64)
void k_graph(const float* __restrict__ H2, const int* __restrict__ nb,
             float* __restrict__ embed)
{
  __shared__ int bounds[2];
  int b = blockIdx.x, c = threadIdx.x;
  if (c < 2){
    int target = b + c;
    int lo = 0, hi = NN;
    while (lo < hi){ int mid = (lo + hi) >> 1; if (nb[mid] < target) lo = mid + 1; else hi = mid; }
    bounds[c] = lo;
  }
  __syncthreads();
  int lo = bounds[0], hi = bounds[1];
  float s = 0.f;
  for (int n = lo; n < hi; ++n) s += H2[(size_t)n*GD + c];
  embed[b*GD + c] = s / fmaxf((float)(hi - lo), 1.f);
}

// ---------------- actor head: one block per batch row ----------------
__global__ __launch_bounds__(256)
void k_head(const float* __restrict__ state, const float* __restrict__ embed,
            const float* __restrict__ fc1w, const float* __restrict__ fc1b,
            const float* __restrict__ fc2w, const float* __restrict__ fc2b,
            const float* __restrict__ mw, const float* __restrict__ mb,
            const float* __restrict__ lw, const float* __restrict__ lb,
            float* __restrict__ out)
{
  int b = blockIdx.x, t = threadIdx.x;
  __shared__ float z[SD + GD];
  __shared__ float h1[HID];
  __shared__ float h2[HID];
  if (t < SD) z[t] = state[b*SD + t];
  else if (t < SD + GD) z[t] = embed[b*GD + (t - SD)];
  __syncthreads();
  float acc = fc1b[t];
  for (int k = 0; k < SD + GD; ++k) acc = fmaf(z[k], fc1w[k*HID + t], acc);
  h1[t] = fmaxf(acc, 0.f);
  __syncthreads();
  acc = fc2b[t];
  for (int k = 0; k < HID; ++k) acc = fmaf(h1[k], fc2w[k*HID + t], acc);
  h2[t] = fmaxf(acc, 0.f);
  __syncthreads();
  if (t < AD){
    float m = mb[t];
    for (int k = 0; k < HID; ++k) m = fmaf(h2[k], mw[k*AD + t], m);
    out[b*AD + t] = m;
  } else if (t < 2*AD){
    int j = t - AD;
    float l = lb[j];
    for (int k = 0; k < HID; ++k) l = fmaf(h2[k], lw[k*AD + j], l);
    out[NB*AD + b*AD + j] = fminf(fmaxf(l, -20.f), 2.f);
  }
}

extern "C" void kernel_launch(void* const* d_in, const int* in_sizes, int n_in,
                              void* d_out, int out_size, void* d_ws, size_t ws_size,
                              hipStream_t stream)
{
  const float* state = (const float*)d_in[0];
  const float* x     = (const float*)d_in[1];
  const int*   eidx  = (const int*)  d_in[2];
  const int*   nb    = (const int*)  d_in[3];
  const float* g1w1  = (const float*)d_in[4];
  const float* g1b1  = (const float*)d_in[5];
  const float* g1w2  = (const float*)d_in[6];
  const float* g1b2  = (const float*)d_in[7];
  const float* g2w1  = (const float*)d_in[8];
  const float* g2b1  = (const float*)d_in[9];
  const float* g2w2  = (const float*)d_in[10];
  const float* g2b2  = (const float*)d_in[11];
  const float* fc1w  = (const float*)d_in[12];
  const float* fc1b  = (const float*)d_in[13];
  const float* fc2w  = (const float*)d_in[14];
  const float* fc2b  = (const float*)d_in[15];
  const float* mw    = (const float*)d_in[16];
  const float* mb    = (const float*)d_in[17];
  const float* lw    = (const float*)d_in[18];
  const float* lb    = (const float*)d_in[19];

  const int* e_src = eidx;        // edge_index[0]
  const int* e_dst = eidx + NE;   // edge_index[1]

  char* p = (char*)d_ws;
  auto alloc = [&](size_t bytes){ char* r = p; p += align256(bytes); return r; };
  int*   cnt    = (int*)  alloc((size_t)NN*4);
  int*   offs   = (int*)  alloc((size_t)NN*4);
  int*   cursor = (int*)  alloc((size_t)NN*4);
  int*   ssrc   = (int*)  alloc((size_t)NE*4);
  int*   bsum   = (int*)  alloc((size_t)SCB*4);
  int*   boff   = (int*)  alloc((size_t)SCB*4);
  float* fA     = (float*)alloc((size_t)NN*GH*4);
  float* fB     = (float*)alloc((size_t)NN*GH*4);
  float* fS     = (float*)alloc((size_t)NN*GH*4);
  float* fH     = (float*)alloc((size_t)NN*GH*4);
  // overlays (lifetimes disjoint):
  float* fC     = fA;                      // [NN,64]
  float* fD     = fA + (size_t)NN*GD;      // [NN,64]
  float* fS2    = fB;                      // [NN,64]
  float* fH2    = fB + (size_t)NN*GD;      // [NN,64]
  float* embed  = fS;                      // [NB,64]

  hipMemsetAsync(cnt, 0, (size_t)NN*4, stream);

  dim3 b256(256), b64(64);
  k_hist   <<<dim3((NE+255)/256), b256, 0, stream>>>(e_dst, cnt);
  k_scan_a <<<dim3(SCB), b256, 0, stream>>>(cnt, bsum);
  k_scan_b <<<dim3(1),   b256, 0, stream>>>(bsum, boff);
  k_scan_c <<<dim3(SCB), b256, 0, stream>>>(cnt, boff, offs, cursor);
  k_scatter<<<dim3((NE+255)/256), b256, 0, stream>>>(e_src, e_dst, cursor, ssrc);

  const int MB = (NN + 63)/64;  // 782
  // Layer 1: A = x @ w1[0:64,:], B = x @ w1[64:128,:]
  k_mgemm<<<dim3(MB,2), b256, 0, stream>>>(x, g1w1,         fA, NN, 64, GH, GH, nullptr, nullptr, 0);
  k_mgemm<<<dim3(MB,2), b256, 0, stream>>>(x, g1w1 + 64*GH, fB, NN, 64, GH, GH, nullptr, nullptr, 0);
  k_edge1<<<dim3(NN), b64, 0, stream>>>(fA, fB, g1b1, offs, cnt, ssrc, fS);
  // h = relu((S @ w2 + cnt*b2)/max(cnt,1))
  k_mgemm<<<dim3(MB,2), b256, 0, stream>>>(fS, g1w2, fH, NN, 128, GH, GH, cnt, g1b2, 1);

  // Layer 2: C = h @ w1[0:128,:], D = h @ w1[128:256,:]
  k_mgemm<<<dim3(MB,1), b256, 0, stream>>>(fH, g2w1,            fC, NN, 128, GD, GD, nullptr, nullptr, 0);
  k_mgemm<<<dim3(MB,1), b256, 0, stream>>>(fH, g2w1 + 128*GD,   fD, NN, 128, GD, GD, nullptr, nullptr, 0);
  k_edge2<<<dim3(NN), b64, 0, stream>>>(fC, fD, g2b1, offs, cnt, ssrc, fS2);
  // h2 = (S2 @ w2 + cnt*b2)/max(cnt,1)   (no relu)
  k_mgemm<<<dim3(MB,1), b256, 0, stream>>>(fS2, g2w2, fH2, NN, 64, GD, GD, cnt, g2b2, 0);

  k_graph<<<dim3(NB), b64, 0, stream>>>(fH2, nb, embed);
  k_head <<<dim3(NB), b256, 0, stream>>>(state, embed, fc1w, fc1b, fc2w, fc2b,
                                         mw, mb, lw, lb, (float*)d_out);
}

// Round 3
// 459.418 us; speedup vs baseline: 1.4062x; 1.1729x over previous
//
#include <hip/hip_runtime.h>

#define NN 50000      // nodes
#define NE 800000     // edges
#define NB 128        // graphs / batch
#define SD 64         // state dim / node dim
#define GH 128        // gnn layer1 width
#define GD 64         // gnn layer2 width
#define HID 256       // actor hidden
#define AD 8          // action dim
#define SCB 196       // scan blocks: 196*256 = 50176 >= NN
#define GCH 128       // nodes per k_gsum chunk

static inline size_t align256(size_t x){ return (x + 255) & ~size_t(255); }

typedef __attribute__((ext_vector_type(8))) short short8v;
typedef __attribute__((ext_vector_type(4))) float f32x4;

// Split fp32 into hi/lo bf16 (truncation; combined rel err ~2^-16).
__device__ inline void bsplit(float f, short& h, short& l){
  unsigned u = __builtin_bit_cast(unsigned, f);
  h = (short)(u >> 16);
  float hif = __builtin_bit_cast(float, u & 0xFFFF0000u);
  float rem = f - hif;   // exact
  l = (short)(__builtin_bit_cast(unsigned, rem) >> 16);
}

// ---------------- CSR build ----------------
__global__ void k_hist(const int* __restrict__ dst, int* __restrict__ cnt){
  int e = blockIdx.x*256 + threadIdx.x;
  if (e < NE) atomicAdd(&cnt[dst[e]], 1);
}

__global__ __launch_bounds__(256)
void k_scan_a(const int* __restrict__ cnt, int* __restrict__ bsum){
  __shared__ int sm[256];
  int t = threadIdx.x;
  int i = blockIdx.x*256 + t;
  int v = (i < NN) ? cnt[i] : 0;
  sm[t] = v; __syncthreads();
  for (int d = 128; d > 0; d >>= 1){
    if (t < d) sm[t] += sm[t + d];
    __syncthreads();
  }
  if (t == 0) bsum[blockIdx.x] = sm[0];
}

__global__ __launch_bounds__(256)
void k_scan_b(const int* __restrict__ bsum, int* __restrict__ boff){
  __shared__ int sm[256];
  int t = threadIdx.x;
  int v = (t < SCB) ? bsum[t] : 0;
  sm[t] = v; __syncthreads();
  for (int d = 1; d < 256; d <<= 1){
    int add = (t >= d) ? sm[t - d] : 0;
    __syncthreads();
    sm[t] += add;
    __syncthreads();
  }
  if (t < SCB) boff[t] = sm[t] - v;   // exclusive
}

__global__ __launch_bounds__(256)
void k_scan_c(const int* __restrict__ cnt, const int* __restrict__ boff,
              int* __restrict__ offs, int* __restrict__ cursor){
  __shared__ int sm[256];
  int t = threadIdx.x;
  int i = blockIdx.x*256 + t;
  int v = (i < NN) ? cnt[i] : 0;
  sm[t] = v; __syncthreads();
  for (int d = 1; d < 256; d <<= 1){
    int add = (t >= d) ? sm[t - d] : 0;
    __syncthreads();
    sm[t] += add;
    __syncthreads();
  }
  if (i < NN){
    int e = sm[t] - v + boff[blockIdx.x];
    offs[i] = e; cursor[i] = e;
  }
}

__global__ void k_scatter(const int* __restrict__ esrc, const int* __restrict__ edst,
                          int* __restrict__ cursor, int* __restrict__ ssrc){
  int e = blockIdx.x*256 + threadIdx.x;
  if (e < NE){
    int p = atomicAdd(&cursor[edst[e]], 1);
    ssrc[p] = esrc[e];
  }
}

// ---------------- split-bf16 MFMA GEMM ----------------
// Out[M, 64*gridDim.y] = post(In[M,K] @ W[K,ldw] cols [n0,n0+64))
// post: if cnt: v=(v+cnt[m]*bias[n])/max(cnt[m],1); if relu: max(v,0)
__global__ __launch_bounds__(256)
void k_mgemm(const float* __restrict__ In, const float* __restrict__ W,
             float* __restrict__ Out, int M, int K, int ldw, int ldo,
             const int* __restrict__ cnt, const float* __restrict__ bias,
             int do_relu)
{
  __shared__ short Ah[64*40], Al[64*40], Bh[64*40], Bl[64*40];
  int tid = threadIdx.x;
  int w = tid >> 6, lane = tid & 63, l15 = tid & 15, quad = lane >> 4;
  int m0 = blockIdx.x*64, n0 = blockIdx.y*64;
  f32x4 acc[4];
  #pragma unroll
  for (int t = 0; t < 4; ++t) acc[t] = (f32x4){0.f,0.f,0.f,0.f};

  for (int k0 = 0; k0 < K; k0 += 32){
    #pragma unroll
    for (int i = 0; i < 2; ++i){
      int s = tid + i*256;        // 0..511 float4 slots
      int m = s >> 3, q = s & 7;  // row, k-quad
      float4 v = make_float4(0.f,0.f,0.f,0.f);
      if (m0 + m < M) v = *reinterpret_cast<const float4*>(&In[(size_t)(m0+m)*K + k0 + q*4]);
      short4 h4, l4;
      bsplit(v.x, h4.x, l4.x); bsplit(v.y, h4.y, l4.y);
      bsplit(v.z, h4.z, l4.z); bsplit(v.w, h4.w, l4.w);
      *reinterpret_cast<short4*>(&Ah[m*40 + q*4]) = h4;
      *reinterpret_cast<short4*>(&Al[m*40 + q*4]) = l4;
    }
    #pragma unroll
    for (int i = 0; i < 2; ++i){
      int s = tid + i*256;          // 0..511
      int r = s >> 4, cq = s & 15;  // k-row, col-quad
      float4 v = *reinterpret_cast<const float4*>(&W[(size_t)(k0+r)*ldw + n0 + cq*4]);
      #pragma unroll
      for (int j = 0; j < 4; ++j){
        short h, l; bsplit((&v.x)[j], h, l);
        Bh[(cq*4+j)*40 + r] = h;
        Bl[(cq*4+j)*40 + r] = l;
      }
    }
    __syncthreads();
    short8v ah = *reinterpret_cast<short8v*>(&Ah[(w*16 + l15)*40 + quad*8]);
    short8v al = *reinterpret_cast<short8v*>(&Al[(w*16 + l15)*40 + quad*8]);
    #pragma unroll
    for (int t = 0; t < 4; ++t){
      short8v bh = *reinterpret_cast<short8v*>(&Bh[(t*16 + l15)*40 + quad*8]);
      short8v bl = *reinterpret_cast<short8v*>(&Bl[(t*16 + l15)*40 + quad*8]);
      acc[t] = __builtin_amdgcn_mfma_f32_16x16x32_bf16(ah, bh, acc[t], 0, 0, 0);
      acc[t] = __builtin_amdgcn_mfma_f32_16x16x32_bf16(ah, bl, acc[t], 0, 0, 0);
      acc[t] = __builtin_amdgcn_mfma_f32_16x16x32_bf16(al, bh, acc[t], 0, 0, 0);
    }
    __syncthreads();
  }
  #pragma unroll
  for (int r = 0; r < 4; ++r){
    int m = m0 + w*16 + quad*4 + r;   // C/D row = quad*4 + reg
    if (m >= M) continue;
    float fcnt = 0.f, inv = 1.f;
    if (cnt){ fcnt = (float)cnt[m]; inv = 1.f / fmaxf(fcnt, 1.f); }
    #pragma unroll
    for (int t = 0; t < 4; ++t){
      int n = n0 + t*16 + l15;        // C/D col = lane&15
      float v = acc[t][r];
      if (cnt) v = (v + fcnt * bias[n]) * inv;
      if (do_relu) v = fmaxf(v, 0.f);
      Out[(size_t)m*ldo + n] = v;
    }
  }
}

// ---------------- edge aggregation, layer 1 (dim 128, 2 ch/lane, 4 nodes/block) ----
__global__ __launch_bounds__(256)
void k_edge1(const float* __restrict__ A, const float* __restrict__ Bm,
             const float* __restrict__ b1, const int* __restrict__ offs,
             const int* __restrict__ cnt, const int* __restrict__ ssrc,
             float* __restrict__ S)
{
  int v = blockIdx.x*4 + (threadIdx.x >> 6);
  if (v >= NN) return;
  int c = threadIdx.x & 63;  // channels 2c, 2c+1
  float2 a  = *reinterpret_cast<const float2*>(&A[(size_t)v*GH + 2*c]);
  float2 bb = *reinterpret_cast<const float2*>(&b1[2*c]);
  float ax = a.x + bb.x, ay = a.y + bb.y;
  int beg = offs[v], n = cnt[v];
  float sx = 0.f, sy = 0.f;
  int snext = (n > 0) ? ssrc[beg] : 0;
  for (int i = 0; i < n; ++i){
    int s = snext;
    if (i + 1 < n) snext = ssrc[beg + i + 1];
    float2 bv = *reinterpret_cast<const float2*>(&Bm[(size_t)s*GH + 2*c]);
    sx += fmaxf(ax + bv.x, 0.f);
    sy += fmaxf(ay + bv.y, 0.f);
  }
  *reinterpret_cast<float2*>(&S[(size_t)v*GH + 2*c]) = make_float2(sx, sy);
}

// ---------------- edge aggregation, layer 2 (dim 64, 1 ch/lane, 4 nodes/block) ----
__global__ __launch_bounds__(256)
void k_edge2(const float* __restrict__ C, const float* __restrict__ D,
             const float* __restrict__ b1, const int* __restrict__ offs,
             const int* __restrict__ cnt, const int* __restrict__ ssrc,
             float* __restrict__ S2)
{
  int v = blockIdx.x*4 + (threadIdx.x >> 6);
  if (v >= NN) return;
  int c = threadIdx.x & 63;
  float a = C[(size_t)v*GD + c] + b1[c];
  int beg = offs[v], n = cnt[v];
  float s = 0.f;
  int snext = (n > 0) ? ssrc[beg] : 0;
  for (int i = 0; i < n; ++i){
    int u = snext;
    if (i + 1 < n) snext = ssrc[beg + i + 1];
    s += fmaxf(a + D[(size_t)u*GD + c], 0.f);
  }
  S2[(size_t)v*GD + c] = s;
}

// ---------------- graph partial sums (atomic, node-parallel) ----------------
__global__ __launch_bounds__(256)
void k_gsum(const float* __restrict__ H2, const int* __restrict__ nb,
            float* __restrict__ gsum)
{
  int c = threadIdx.x & 63;
  int w = threadIdx.x >> 6;      // 0..3
  int base = blockIdx.x * GCH;
  int end = base + GCH; if (end > NN) end = NN;
  float acc = 0.f;
  int cur = -1;
  for (int i = base + w; i < end; i += 4){
    int g = nb[i];
    if (g != cur){
      if (cur >= 0) atomicAdd(&gsum[cur*GD + c], acc);
      cur = g; acc = 0.f;
    }
    acc += H2[(size_t)i*GD + c];
  }
  if (cur >= 0) atomicAdd(&gsum[cur*GD + c], acc);
}

// ---------------- actor head: one block per batch row (divide fused here) -----
__global__ __launch_bounds__(256)
void k_head(const float* __restrict__ state, const float* __restrict__ gsum,
            const int* __restrict__ nb,
            const float* __restrict__ fc1w, const float* __restrict__ fc1b,
            const float* __restrict__ fc2w, const float* __restrict__ fc2b,
            const float* __restrict__ mw, const float* __restrict__ mb,
            const float* __restrict__ lw, const float* __restrict__ lb,
            float* __restrict__ out)
{
  int b = blockIdx.x, t = threadIdx.x;
  __shared__ float z[SD + GD];
  __shared__ float h1[HID];
  __shared__ float h2[HID];
  __shared__ int bounds[2];
  if (t < 2){
    int target = b + t;
    int lo = 0, hi = NN;
    while (lo < hi){ int mid = (lo + hi) >> 1; if (nb[mid] < target) lo = mid + 1; else hi = mid; }
    bounds[t] = lo;
  }
  if (t < SD) z[t] = state[b*SD + t];
  __syncthreads();
  if (t >= SD && t < SD + GD){
    float n = (float)(bounds[1] - bounds[0]);
    z[t] = gsum[b*GD + (t - SD)] / fmaxf(n, 1.f);
  }
  __syncthreads();
  float acc = fc1b[t];
  for (int k = 0; k < SD + GD; ++k) acc = fmaf(z[k], fc1w[k*HID + t], acc);
  h1[t] = fmaxf(acc, 0.f);
  __syncthreads();
  acc = fc2b[t];
  for (int k = 0; k < HID; ++k) acc = fmaf(h1[k], fc2w[k*HID + t], acc);
  h2[t] = fmaxf(acc, 0.f);
  __syncthreads();
  if (t < AD){
    float m = mb[t];
    for (int k = 0; k < HID; ++k) m = fmaf(h2[k], mw[k*AD + t], m);
    out[b*AD + t] = m;
  } else if (t < 2*AD){
    int j = t - AD;
    float l = lb[j];
    for (int k = 0; k < HID; ++k) l = fmaf(h2[k], lw[k*AD + j], l);
    out[NB*AD + b*AD + j] = fminf(fmaxf(l, -20.f), 2.f);
  }
}

extern "C" void kernel_launch(void* const* d_in, const int* in_sizes, int n_in,
                              void* d_out, int out_size, void* d_ws, size_t ws_size,
                              hipStream_t stream)
{
  const float* state = (const float*)d_in[0];
  const float* x     = (const float*)d_in[1];
  const int*   eidx  = (const int*)  d_in[2];
  const int*   nb    = (const int*)  d_in[3];
  const float* g1w1  = (const float*)d_in[4];
  const float* g1b1  = (const float*)d_in[5];
  const float* g1w2  = (const float*)d_in[6];
  const float* g1b2  = (const float*)d_in[7];
  const float* g2w1  = (const float*)d_in[8];
  const float* g2b1  = (const float*)d_in[9];
  const float* g2w2  = (const float*)d_in[10];
  const float* g2b2  = (const float*)d_in[11];
  const float* fc1w  = (const float*)d_in[12];
  const float* fc1b  = (const float*)d_in[13];
  const float* fc2w  = (const float*)d_in[14];
  const float* fc2b  = (const float*)d_in[15];
  const float* mw    = (const float*)d_in[16];
  const float* mb    = (const float*)d_in[17];
  const float* lw    = (const float*)d_in[18];
  const float* lb    = (const float*)d_in[19];

  const int* e_src = eidx;        // edge_index[0]
  const int* e_dst = eidx + NE;   // edge_index[1]

  char* p = (char*)d_ws;
  auto alloc = [&](size_t bytes){ char* r = p; p += align256(bytes); return r; };
  int*   cnt    = (int*)  alloc((size_t)NN*4);
  int*   offs   = (int*)  alloc((size_t)NN*4);
  int*   cursor = (int*)  alloc((size_t)NN*4);
  int*   ssrc   = (int*)  alloc((size_t)NE*4);
  int*   bsum   = (int*)  alloc((size_t)SCB*4);
  int*   boff   = (int*)  alloc((size_t)SCB*4);
  float* gsum   = (float*)alloc((size_t)NB*GD*4);
  float* fA     = (float*)alloc((size_t)NN*GH*4);
  float* fB     = (float*)alloc((size_t)NN*GH*4);
  float* fS     = (float*)alloc((size_t)NN*GH*4);
  float* fH     = (float*)alloc((size_t)NN*GH*4);
  // overlays (lifetimes disjoint):
  float* fC     = fA;                      // [NN,64]
  float* fD     = fA + (size_t)NN*GD;      // [NN,64]
  float* fS2    = fB;                      // [NN,64]
  float* fH2    = fB + (size_t)NN*GD;      // [NN,64]

  hipMemsetAsync(cnt, 0, (size_t)NN*4, stream);
  hipMemsetAsync(gsum, 0, (size_t)NB*GD*4, stream);

  dim3 b256(256), b64(64);
  k_hist   <<<dim3((NE+255)/256), b256, 0, stream>>>(e_dst, cnt);
  k_scan_a <<<dim3(SCB), b256, 0, stream>>>(cnt, bsum);
  k_scan_b <<<dim3(1),   b256, 0, stream>>>(bsum, boff);
  k_scan_c <<<dim3(SCB), b256, 0, stream>>>(cnt, boff, offs, cursor);
  k_scatter<<<dim3((NE+255)/256), b256, 0, stream>>>(e_src, e_dst, cursor, ssrc);

  const int MB = (NN + 63)/64;  // 782
  // Layer 1: A = x @ w1[0:64,:], B = x @ w1[64:128,:]
  k_mgemm<<<dim3(MB,2), b256, 0, stream>>>(x, g1w1,         fA, NN, 64, GH, GH, nullptr, nullptr, 0);
  k_mgemm<<<dim3(MB,2), b256, 0, stream>>>(x, g1w1 + 64*GH, fB, NN, 64, GH, GH, nullptr, nullptr, 0);
  k_edge1<<<dim3((NN+3)/4), b256, 0, stream>>>(fA, fB, g1b1, offs, cnt, ssrc, fS);
  // h = relu((S @ w2 + cnt*b2)/max(cnt,1))
  k_mgemm<<<dim3(MB,2), b256, 0, stream>>>(fS, g1w2, fH, NN, 128, GH, GH, cnt, g1b2, 1);

  // Layer 2: C = h @ w1[0:128,:], D = h @ w1[128:256,:]
  k_mgemm<<<dim3(MB,1), b256, 0, stream>>>(fH, g2w1,            fC, NN, 128, GD, GD, nullptr, nullptr, 0);
  k_mgemm<<<dim3(MB,1), b256, 0, stream>>>(fH, g2w1 + 128*GD,   fD, NN, 128, GD, GD, nullptr, nullptr, 0);
  k_edge2<<<dim3((NN+3)/4), b256, 0, stream>>>(fC, fD, g2b1, offs, cnt, ssrc, fS2);
  // h2 = (S2 @ w2 + cnt*b2)/max(cnt,1)   (no relu)
  k_mgemm<<<dim3(MB,1), b256, 0, stream>>>(fS2, g2w2, fH2, NN, 64, GD, GD, cnt, g2b2, 0);

  k_gsum<<<dim3((NN+GCH-1)/GCH), b256, 0, stream>>>(fH2, nb, gsum);
  k_head<<<dim3(NB), b256, 0, stream>>>(state, gsum, nb, fc1w, fc1b, fc2w, fc2b,
                                        mw, mb, lw, lb, (float*)d_out);
}

// Round 4
// 436.368 us; speedup vs baseline: 1.4805x; 1.0528x over previous
//
#include <hip/hip_runtime.h>

#define NN 50000      // nodes
#define NE 800000     // edges
#define NB 128        // graphs / batch
#define SD 64         // state dim / node dim
#define GH 128        // gnn layer1 width
#define GD 64         // gnn layer2 width
#define HID 256       // actor hidden
#define AD 8          // action dim
#define SCB 196       // scan blocks: 196*256 = 50176 >= NN
#define GCH 128       // nodes per k_gsum chunk

static inline size_t align256(size_t x){ return (x + 255) & ~size_t(255); }

typedef __attribute__((ext_vector_type(8))) short short8v;
typedef __attribute__((ext_vector_type(4))) float f32x4;

// Split fp32 into hi/lo bf16 (truncation; combined rel err ~2^-16).
__device__ inline void bsplit(float f, short& h, short& l){
  unsigned u = __builtin_bit_cast(unsigned, f);
  h = (short)(u >> 16);
  float hif = __builtin_bit_cast(float, u & 0xFFFF0000u);
  float rem = f - hif;   // exact
  l = (short)(__builtin_bit_cast(unsigned, rem) >> 16);
}

__device__ inline unsigned short f2bf(float f){  // RNE
  unsigned u = __builtin_bit_cast(unsigned, f);
  return (unsigned short)((u + 0x7FFFu + ((u >> 16) & 1u)) >> 16);
}
__device__ inline float bf2f(unsigned short h){
  return __builtin_bit_cast(float, ((unsigned)h) << 16);
}

// ---------------- CSR build ----------------
__global__ void k_hist(const int* __restrict__ dst, int* __restrict__ cnt){
  int e = blockIdx.x*256 + threadIdx.x;
  if (e < NE) atomicAdd(&cnt[dst[e]], 1);
}

__global__ __launch_bounds__(256)
void k_scan_a(const int* __restrict__ cnt, int* __restrict__ bsum){
  __shared__ int sm[256];
  int t = threadIdx.x;
  int i = blockIdx.x*256 + t;
  int v = (i < NN) ? cnt[i] : 0;
  sm[t] = v; __syncthreads();
  for (int d = 128; d > 0; d >>= 1){
    if (t < d) sm[t] += sm[t + d];
    __syncthreads();
  }
  if (t == 0) bsum[blockIdx.x] = sm[0];
}

__global__ __launch_bounds__(256)
void k_scan_b(const int* __restrict__ bsum, int* __restrict__ boff){
  __shared__ int sm[256];
  int t = threadIdx.x;
  int v = (t < SCB) ? bsum[t] : 0;
  sm[t] = v; __syncthreads();
  for (int d = 1; d < 256; d <<= 1){
    int add = (t >= d) ? sm[t - d] : 0;
    __syncthreads();
    sm[t] += add;
    __syncthreads();
  }
  if (t < SCB) boff[t] = sm[t] - v;   // exclusive
}

__global__ __launch_bounds__(256)
void k_scan_c(const int* __restrict__ cnt, const int* __restrict__ boff,
              int* __restrict__ offs, int* __restrict__ cursor){
  __shared__ int sm[256];
  int t = threadIdx.x;
  int i = blockIdx.x*256 + t;
  int v = (i < NN) ? cnt[i] : 0;
  sm[t] = v; __syncthreads();
  for (int d = 1; d < 256; d <<= 1){
    int add = (t >= d) ? sm[t - d] : 0;
    __syncthreads();
    sm[t] += add;
    __syncthreads();
  }
  if (i < NN){
    int e = sm[t] - v + boff[blockIdx.x];
    offs[i] = e; cursor[i] = e;
  }
}

__global__ void k_scatter(const int* __restrict__ esrc, const int* __restrict__ edst,
                          int* __restrict__ cursor, int* __restrict__ ssrc){
  int e = blockIdx.x*256 + threadIdx.x;
  if (e < NE){
    int p = atomicAdd(&cursor[edst[e]], 1);
    ssrc[p] = esrc[e];
  }
}

// ---------------- split-bf16 MFMA GEMM ----------------
// Out[M, 64*gridDim.y] = post(In[M,K] @ W[K,ldw] cols [n0,n0+64))
// post: if cnt: v=(v+cnt[m]*bias[n])/max(cnt[m],1); if relu: max(v,0)
// OB: 0 -> fp32 out, 1 -> bf16(RNE) out
template<int OB>
__global__ __launch_bounds__(256)
void k_mgemm(const float* __restrict__ In, const float* __restrict__ W,
             void* __restrict__ OutV, int M, int K, int ldw, int ldo,
             const int* __restrict__ cnt, const float* __restrict__ bias,
             int do_relu)
{
  __shared__ short Ah[64*40], Al[64*40], Bh[64*40], Bl[64*40];
  int tid = threadIdx.x;
  int w = tid >> 6, lane = tid & 63, l15 = tid & 15, quad = lane >> 4;
  int m0 = blockIdx.x*64, n0 = blockIdx.y*64;
  f32x4 acc[4];
  #pragma unroll
  for (int t = 0; t < 4; ++t) acc[t] = (f32x4){0.f,0.f,0.f,0.f};

  for (int k0 = 0; k0 < K; k0 += 32){
    #pragma unroll
    for (int i = 0; i < 2; ++i){
      int s = tid + i*256;        // 0..511 float4 slots
      int m = s >> 3, q = s & 7;  // row, k-quad
      float4 v = make_float4(0.f,0.f,0.f,0.f);
      if (m0 + m < M) v = *reinterpret_cast<const float4*>(&In[(size_t)(m0+m)*K + k0 + q*4]);
      short4 h4, l4;
      bsplit(v.x, h4.x, l4.x); bsplit(v.y, h4.y, l4.y);
      bsplit(v.z, h4.z, l4.z); bsplit(v.w, h4.w, l4.w);
      *reinterpret_cast<short4*>(&Ah[m*40 + q*4]) = h4;
      *reinterpret_cast<short4*>(&Al[m*40 + q*4]) = l4;
    }
    #pragma unroll
    for (int i = 0; i < 2; ++i){
      int s = tid + i*256;          // 0..511
      int r = s >> 4, cq = s & 15;  // k-row, col-quad
      float4 v = *reinterpret_cast<const float4*>(&W[(size_t)(k0+r)*ldw + n0 + cq*4]);
      #pragma unroll
      for (int j = 0; j < 4; ++j){
        short h, l; bsplit((&v.x)[j], h, l);
        Bh[(cq*4+j)*40 + r] = h;
        Bl[(cq*4+j)*40 + r] = l;
      }
    }
    __syncthreads();
    short8v ah = *reinterpret_cast<short8v*>(&Ah[(w*16 + l15)*40 + quad*8]);
    short8v al = *reinterpret_cast<short8v*>(&Al[(w*16 + l15)*40 + quad*8]);
    #pragma unroll
    for (int t = 0; t < 4; ++t){
      short8v bh = *reinterpret_cast<short8v*>(&Bh[(t*16 + l15)*40 + quad*8]);
      short8v bl = *reinterpret_cast<short8v*>(&Bl[(t*16 + l15)*40 + quad*8]);
      acc[t] = __builtin_amdgcn_mfma_f32_16x16x32_bf16(ah, bh, acc[t], 0, 0, 0);
      acc[t] = __builtin_amdgcn_mfma_f32_16x16x32_bf16(ah, bl, acc[t], 0, 0, 0);
      acc[t] = __builtin_amdgcn_mfma_f32_16x16x32_bf16(al, bh, acc[t], 0, 0, 0);
    }
    __syncthreads();
  }
  #pragma unroll
  for (int r = 0; r < 4; ++r){
    int m = m0 + w*16 + quad*4 + r;   // C/D row = quad*4 + reg
    if (m >= M) continue;
    float fcnt = 0.f, inv = 1.f;
    if (cnt){ fcnt = (float)cnt[m]; inv = 1.f / fmaxf(fcnt, 1.f); }
    #pragma unroll
    for (int t = 0; t < 4; ++t){
      int n = n0 + t*16 + l15;        // C/D col = lane&15
      float v = acc[t][r];
      if (cnt) v = (v + fcnt * bias[n]) * inv;
      if (do_relu) v = fmaxf(v, 0.f);
      if (OB) ((unsigned short*)OutV)[(size_t)m*ldo + n] = f2bf(v);
      else    ((float*)OutV)[(size_t)m*ldo + n] = v;
    }
  }
}

// ------- edge aggregation, layer 1 (dim 128, 2 ch/lane, 4 nodes/block, bf16 in) -------
__global__ __launch_bounds__(256)
void k_edge1(const unsigned short* __restrict__ A, const unsigned short* __restrict__ Bm,
             const float* __restrict__ b1, const int* __restrict__ offs,
             const int* __restrict__ cnt, const int* __restrict__ ssrc,
             float* __restrict__ S)
{
  int v = blockIdx.x*4 + (threadIdx.x >> 6);
  if (v >= NN) return;
  int c = threadIdx.x & 63;  // channels 2c, 2c+1
  ushort2 a2 = *reinterpret_cast<const ushort2*>(&A[(size_t)v*GH + 2*c]);
  float2 bb = *reinterpret_cast<const float2*>(&b1[2*c]);
  float ax = bf2f(a2.x) + bb.x, ay = bf2f(a2.y) + bb.y;
  int beg = offs[v], n = cnt[v];
  float sx = 0.f, sy = 0.f;
  int i = 0;
  for (; i + 2 <= n; i += 2){
    int s0 = ssrc[beg + i];
    int s1 = ssrc[beg + i + 1];
    ushort2 b0 = *reinterpret_cast<const ushort2*>(&Bm[(size_t)s0*GH + 2*c]);
    ushort2 b1v = *reinterpret_cast<const ushort2*>(&Bm[(size_t)s1*GH + 2*c]);
    sx += fmaxf(ax + bf2f(b0.x), 0.f) + fmaxf(ax + bf2f(b1v.x), 0.f);
    sy += fmaxf(ay + bf2f(b0.y), 0.f) + fmaxf(ay + bf2f(b1v.y), 0.f);
  }
  if (i < n){
    int s0 = ssrc[beg + i];
    ushort2 b0 = *reinterpret_cast<const ushort2*>(&Bm[(size_t)s0*GH + 2*c]);
    sx += fmaxf(ax + bf2f(b0.x), 0.f);
    sy += fmaxf(ay + bf2f(b0.y), 0.f);
  }
  *reinterpret_cast<float2*>(&S[(size_t)v*GH + 2*c]) = make_float2(sx, sy);
}

// ------- edge aggregation, layer 2 (dim 64, 1 ch/lane, 4 nodes/block, bf16 in) -------
__global__ __launch_bounds__(256)
void k_edge2(const unsigned short* __restrict__ C, const unsigned short* __restrict__ D,
             const float* __restrict__ b1, const int* __restrict__ offs,
             const int* __restrict__ cnt, const int* __restrict__ ssrc,
             float* __restrict__ S2)
{
  int v = blockIdx.x*4 + (threadIdx.x >> 6);
  if (v >= NN) return;
  int c = threadIdx.x & 63;
  float a = bf2f(C[(size_t)v*GD + c]) + b1[c];
  int beg = offs[v], n = cnt[v];
  float s = 0.f;
  int i = 0;
  for (; i + 2 <= n; i += 2){
    int u0 = ssrc[beg + i];
    int u1 = ssrc[beg + i + 1];
    float d0 = bf2f(D[(size_t)u0*GD + c]);
    float d1 = bf2f(D[(size_t)u1*GD + c]);
    s += fmaxf(a + d0, 0.f) + fmaxf(a + d1, 0.f);
  }
  if (i < n){
    int u0 = ssrc[beg + i];
    s += fmaxf(a + bf2f(D[(size_t)u0*GD + c]), 0.f);
  }
  S2[(size_t)v*GD + c] = s;
}

// ---------------- graph partial sums (atomic, node-parallel) ----------------
__global__ __launch_bounds__(256)
void k_gsum(const float* __restrict__ H2, const int* __restrict__ nb,
            float* __restrict__ gsum)
{
  int c = threadIdx.x & 63;
  int w = threadIdx.x >> 6;      // 0..3
  int base = blockIdx.x * GCH;
  int end = base + GCH; if (end > NN) end = NN;
  float acc = 0.f;
  int cur = -1;
  for (int i = base + w; i < end; i += 4){
    int g = nb[i];
    if (g != cur){
      if (cur >= 0) atomicAdd(&gsum[cur*GD + c], acc);
      cur = g; acc = 0.f;
    }
    acc += H2[(size_t)i*GD + c];
  }
  if (cur >= 0) atomicAdd(&gsum[cur*GD + c], acc);
}

// ---------------- actor head: one block per batch row (divide fused here) -----
__global__ __launch_bounds__(256)
void k_head(const float* __restrict__ state, const float* __restrict__ gsum,
            const int* __restrict__ nb,
            const float* __restrict__ fc1w, const float* __restrict__ fc1b,
            const float* __restrict__ fc2w, const float* __restrict__ fc2b,
            const float* __restrict__ mw, const float* __restrict__ mb,
            const float* __restrict__ lw, const float* __restrict__ lb,
            float* __restrict__ out)
{
  int b = blockIdx.x, t = threadIdx.x;
  __shared__ float z[SD + GD];
  __shared__ float h1[HID];
  __shared__ float h2[HID];
  __shared__ int bounds[2];
  if (t < 2){
    int target = b + t;
    int lo = 0, hi = NN;
    while (lo < hi){ int mid = (lo + hi) >> 1; if (nb[mid] < target) lo = mid + 1; else hi = mid; }
    bounds[t] = lo;
  }
  if (t < SD) z[t] = state[b*SD + t];
  __syncthreads();
  if (t >= SD && t < SD + GD){
    float n = (float)(bounds[1] - bounds[0]);
    z[t] = gsum[b*GD + (t - SD)] / fmaxf(n, 1.f);
  }
  __syncthreads();
  float acc = fc1b[t];
  for (int k = 0; k < SD + GD; ++k) acc = fmaf(z[k], fc1w[k*HID + t], acc);
  h1[t] = fmaxf(acc, 0.f);
  __syncthreads();
  acc = fc2b[t];
  for (int k = 0; k < HID; ++k) acc = fmaf(h1[k], fc2w[k*HID + t], acc);
  h2[t] = fmaxf(acc, 0.f);
  __syncthreads();
  if (t < AD){
    float m = mb[t];
    for (int k = 0; k < HID; ++k) m = fmaf(h2[k], mw[k*AD + t], m);
    out[b*AD + t] = m;
  } else if (t < 2*AD){
    int j = t - AD;
    float l = lb[j];
    for (int k = 0; k < HID; ++k) l = fmaf(h2[k], lw[k*AD + j], l);
    out[NB*AD + b*AD + j] = fminf(fmaxf(l, -20.f), 2.f);
  }
}

extern "C" void kernel_launch(void* const* d_in, const int* in_sizes, int n_in,
                              void* d_out, int out_size, void* d_ws, size_t ws_size,
                              hipStream_t stream)
{
  const float* state = (const float*)d_in[0];
  const float* x     = (const float*)d_in[1];
  const int*   eidx  = (const int*)  d_in[2];
  const int*   nb    = (const int*)  d_in[3];
  const float* g1w1  = (const float*)d_in[4];
  const float* g1b1  = (const float*)d_in[5];
  const float* g1w2  = (const float*)d_in[6];
  const float* g1b2  = (const float*)d_in[7];
  const float* g2w1  = (const float*)d_in[8];
  const float* g2b1  = (const float*)d_in[9];
  const float* g2w2  = (const float*)d_in[10];
  const float* g2b2  = (const float*)d_in[11];
  const float* fc1w  = (const float*)d_in[12];
  const float* fc1b  = (const float*)d_in[13];
  const float* fc2w  = (const float*)d_in[14];
  const float* fc2b  = (const float*)d_in[15];
  const float* mw    = (const float*)d_in[16];
  const float* mb    = (const float*)d_in[17];
  const float* lw    = (const float*)d_in[18];
  const float* lb    = (const float*)d_in[19];

  const int* e_src = eidx;        // edge_index[0]
  const int* e_dst = eidx + NE;   // edge_index[1]

  char* p = (char*)d_ws;
  auto alloc = [&](size_t bytes){ char* r = p; p += align256(bytes); return r; };
  int*   cnt    = (int*)  alloc((size_t)NN*4);
  int*   offs   = (int*)  alloc((size_t)NN*4);
  int*   cursor = (int*)  alloc((size_t)NN*4);
  int*   ssrc   = (int*)  alloc((size_t)NE*4);
  int*   bsum   = (int*)  alloc((size_t)SCB*4);
  int*   boff   = (int*)  alloc((size_t)SCB*4);
  float* gsum   = (float*)alloc((size_t)NB*GD*4);
  unsigned short* fA = (unsigned short*)alloc((size_t)NN*GH*2);   // bf16 [NN,128]
  unsigned short* fB = (unsigned short*)alloc((size_t)NN*GH*2);   // bf16 [NN,128]
  float* fS     = (float*)alloc((size_t)NN*GH*4);                 // fp32 [NN,128]
  float* fH     = (float*)alloc((size_t)NN*GH*4);                 // fp32 [NN,128]
  // overlays (lifetimes disjoint):
  unsigned short* fC = fA;                          // bf16 [NN,64]
  unsigned short* fD = fA + (size_t)NN*GD;          // bf16 [NN,64]
  float* fS2    = (float*)fB;                       // fp32 [NN,64] (fits: NN*GH*2 bytes)
  float* fH2    = fS;                               // fp32 [NN,64]

  hipMemsetAsync(cnt, 0, (size_t)NN*4, stream);
  hipMemsetAsync(gsum, 0, (size_t)NB*GD*4, stream);

  dim3 b256(256);
  k_hist   <<<dim3((NE+255)/256), b256, 0, stream>>>(e_dst, cnt);
  k_scan_a <<<dim3(SCB), b256, 0, stream>>>(cnt, bsum);
  k_scan_b <<<dim3(1),   b256, 0, stream>>>(bsum, boff);
  k_scan_c <<<dim3(SCB), b256, 0, stream>>>(cnt, boff, offs, cursor);
  k_scatter<<<dim3((NE+255)/256), b256, 0, stream>>>(e_src, e_dst, cursor, ssrc);

  const int MB = (NN + 63)/64;  // 782
  // Layer 1: A = x @ w1[0:64,:], B = x @ w1[64:128,:]  (bf16 out)
  k_mgemm<1><<<dim3(MB,2), b256, 0, stream>>>(x, g1w1,         fA, NN, 64, GH, GH, nullptr, nullptr, 0);
  k_mgemm<1><<<dim3(MB,2), b256, 0, stream>>>(x, g1w1 + 64*GH, fB, NN, 64, GH, GH, nullptr, nullptr, 0);
  k_edge1<<<dim3((NN+3)/4), b256, 0, stream>>>(fA, fB, g1b1, offs, cnt, ssrc, fS);
  // h = relu((S @ w2 + cnt*b2)/max(cnt,1))  (fp32 out)
  k_mgemm<0><<<dim3(MB,2), b256, 0, stream>>>(fS, g1w2, fH, NN, 128, GH, GH, cnt, g1b2, 1);

  // Layer 2: C = h @ w1[0:128,:], D = h @ w1[128:256,:]  (bf16 out)
  k_mgemm<1><<<dim3(MB,1), b256, 0, stream>>>(fH, g2w1,            fC, NN, 128, GD, GD, nullptr, nullptr, 0);
  k_mgemm<1><<<dim3(MB,1), b256, 0, stream>>>(fH, g2w1 + 128*GD,   fD, NN, 128, GD, GD, nullptr, nullptr, 0);
  k_edge2<<<dim3((NN+3)/4), b256, 0, stream>>>(fC, fD, g2b1, offs, cnt, ssrc, fS2);
  // h2 = (S2 @ w2 + cnt*b2)/max(cnt,1)   (no relu, fp32 out)
  k_mgemm<0><<<dim3(MB,1), b256, 0, stream>>>(fS2, g2w2, fH2, NN, 64, GD, GD, cnt, g2b2, 0);

  k_gsum<<<dim3((NN+GCH-1)/GCH), b256, 0, stream>>>(fH2, nb, gsum);
  k_head<<<dim3(NB), b256, 0, stream>>>(state, gsum, nb, fc1w, fc1b, fc2w, fc2b,
                                        mw, mb, lw, lb, (float*)d_out);
}

// Round 5
// 358.691 us; speedup vs baseline: 1.8011x; 1.2166x over previous
//
#include <hip/hip_runtime.h>

#define NN 50000      // nodes
#define NE 800000     // edges
#define NB 128        // graphs / batch
#define SD 64         // state dim / node dim
#define GH 128        // gnn layer1 width
#define GD 64         // gnn layer2 width
#define HID 256       // actor hidden
#define AD 8          // action dim
#define SCB 196       // scan blocks: 196*256 = 50176 >= NN
#define GCH 128       // nodes per k_gsum chunk

static inline size_t align256(size_t x){ return (x + 255) & ~size_t(255); }

typedef __attribute__((ext_vector_type(8))) short short8v;
typedef __attribute__((ext_vector_type(4))) float f32x4;

// Split fp32 into hi/lo bf16 (truncation; combined rel err ~2^-16).
__device__ inline void bsplit(float f, short& h, short& l){
  unsigned u = __builtin_bit_cast(unsigned, f);
  h = (short)(u >> 16);
  float hif = __builtin_bit_cast(float, u & 0xFFFF0000u);
  float rem = f - hif;   // exact
  l = (short)(__builtin_bit_cast(unsigned, rem) >> 16);
}

__device__ inline unsigned short f2bf(float f){  // RNE
  unsigned u = __builtin_bit_cast(unsigned, f);
  return (unsigned short)((u + 0x7FFFu + ((u >> 16) & 1u)) >> 16);
}
__device__ inline float bf2f(unsigned short h){
  return __builtin_bit_cast(float, ((unsigned)h) << 16);
}

// ---------------- CSR build (rank trick: no cursor atomics in placement) ------
__global__ void k_hist(const int* __restrict__ dst, int* __restrict__ cnt,
                       int* __restrict__ rank){
  int e = blockIdx.x*1024 + threadIdx.x;
  #pragma unroll
  for (int j = 0; j < 4; ++j){
    int ee = e + j*256;
    if (ee < NE) rank[ee] = atomicAdd(&cnt[dst[ee]], 1);
  }
}

__global__ __launch_bounds__(256)
void k_scan_a(const int* __restrict__ cnt, int* __restrict__ bsum){
  __shared__ int sm[256];
  int t = threadIdx.x;
  int i = blockIdx.x*256 + t;
  int v = (i < NN) ? cnt[i] : 0;
  sm[t] = v; __syncthreads();
  for (int d = 128; d > 0; d >>= 1){
    if (t < d) sm[t] += sm[t + d];
    __syncthreads();
  }
  if (t == 0) bsum[blockIdx.x] = sm[0];
}

__global__ __launch_bounds__(256)
void k_scan_b(const int* __restrict__ bsum, int* __restrict__ boff){
  __shared__ int sm[256];
  int t = threadIdx.x;
  int v = (t < SCB) ? bsum[t] : 0;
  sm[t] = v; __syncthreads();
  for (int d = 1; d < 256; d <<= 1){
    int add = (t >= d) ? sm[t - d] : 0;
    __syncthreads();
    sm[t] += add;
    __syncthreads();
  }
  if (t < SCB) boff[t] = sm[t] - v;   // exclusive
}

__global__ __launch_bounds__(256)
void k_scan_c(const int* __restrict__ cnt, const int* __restrict__ boff,
              int* __restrict__ offs){
  __shared__ int sm[256];
  int t = threadIdx.x;
  int i = blockIdx.x*256 + t;
  int v = (i < NN) ? cnt[i] : 0;
  sm[t] = v; __syncthreads();
  for (int d = 1; d < 256; d <<= 1){
    int add = (t >= d) ? sm[t - d] : 0;
    __syncthreads();
    sm[t] += add;
    __syncthreads();
  }
  if (i < NN) offs[i] = sm[t] - v + boff[blockIdx.x];
}

__global__ void k_place(const int* __restrict__ esrc, const int* __restrict__ edst,
                        const int* __restrict__ offs, const int* __restrict__ rank,
                        int* __restrict__ ssrc){
  int e = blockIdx.x*1024 + threadIdx.x;
  #pragma unroll
  for (int j = 0; j < 4; ++j){
    int ee = e + j*256;
    if (ee < NE) ssrc[offs[edst[ee]] + rank[ee]] = esrc[ee];
  }
}

// ---------------- split-bf16 MFMA GEMM (z-fused pairs) ----------------
// z = blockIdx.z selects (W0,Out0) or (W1,Out1).
// post: if cnt: v=(v+cnt[m]*bias[n])/max(cnt[m],1); if relu: max(v,0)
// OB: 0 -> fp32 out, 1 -> bf16(RNE) out
template<int OB>
__global__ __launch_bounds__(256)
void k_mgemm(const float* __restrict__ In,
             const float* __restrict__ W0, void* __restrict__ Out0,
             const float* __restrict__ W1, void* __restrict__ Out1,
             int M, int K, int ldw, int ldo,
             const int* __restrict__ cnt, const float* __restrict__ bias,
             int do_relu)
{
  const float* W = (blockIdx.z == 0) ? W0 : W1;
  void* OutV     = (blockIdx.z == 0) ? Out0 : Out1;
  __shared__ short Ah[64*40], Al[64*40], Bh[64*40], Bl[64*40];
  int tid = threadIdx.x;
  int w = tid >> 6, lane = tid & 63, l15 = tid & 15, quad = lane >> 4;
  int m0 = blockIdx.x*64, n0 = blockIdx.y*64;
  f32x4 acc[4];
  #pragma unroll
  for (int t = 0; t < 4; ++t) acc[t] = (f32x4){0.f,0.f,0.f,0.f};

  for (int k0 = 0; k0 < K; k0 += 32){
    #pragma unroll
    for (int i = 0; i < 2; ++i){
      int s = tid + i*256;        // 0..511 float4 slots
      int m = s >> 3, q = s & 7;  // row, k-quad
      float4 v = make_float4(0.f,0.f,0.f,0.f);
      if (m0 + m < M) v = *reinterpret_cast<const float4*>(&In[(size_t)(m0+m)*K + k0 + q*4]);
      short4 h4, l4;
      bsplit(v.x, h4.x, l4.x); bsplit(v.y, h4.y, l4.y);
      bsplit(v.z, h4.z, l4.z); bsplit(v.w, h4.w, l4.w);
      *reinterpret_cast<short4*>(&Ah[m*40 + q*4]) = h4;
      *reinterpret_cast<short4*>(&Al[m*40 + q*4]) = l4;
    }
    #pragma unroll
    for (int i = 0; i < 2; ++i){
      int s = tid + i*256;          // 0..511
      int r = s >> 4, cq = s & 15;  // k-row, col-quad
      float4 v = *reinterpret_cast<const float4*>(&W[(size_t)(k0+r)*ldw + n0 + cq*4]);
      #pragma unroll
      for (int j = 0; j < 4; ++j){
        short h, l; bsplit((&v.x)[j], h, l);
        Bh[(cq*4+j)*40 + r] = h;
        Bl[(cq*4+j)*40 + r] = l;
      }
    }
    __syncthreads();
    short8v ah = *reinterpret_cast<short8v*>(&Ah[(w*16 + l15)*40 + quad*8]);
    short8v al = *reinterpret_cast<short8v*>(&Al[(w*16 + l15)*40 + quad*8]);
    #pragma unroll
    for (int t = 0; t < 4; ++t){
      short8v bh = *reinterpret_cast<short8v*>(&Bh[(t*16 + l15)*40 + quad*8]);
      short8v bl = *reinterpret_cast<short8v*>(&Bl[(t*16 + l15)*40 + quad*8]);
      acc[t] = __builtin_amdgcn_mfma_f32_16x16x32_bf16(ah, bh, acc[t], 0, 0, 0);
      acc[t] = __builtin_amdgcn_mfma_f32_16x16x32_bf16(ah, bl, acc[t], 0, 0, 0);
      acc[t] = __builtin_amdgcn_mfma_f32_16x16x32_bf16(al, bh, acc[t], 0, 0, 0);
    }
    __syncthreads();
  }
  #pragma unroll
  for (int r = 0; r < 4; ++r){
    int m = m0 + w*16 + quad*4 + r;   // C/D row = quad*4 + reg
    if (m >= M) continue;
    float fcnt = 0.f, inv = 1.f;
    if (cnt){ fcnt = (float)cnt[m]; inv = 1.f / fmaxf(fcnt, 1.f); }
    #pragma unroll
    for (int t = 0; t < 4; ++t){
      int n = n0 + t*16 + l15;        // C/D col = lane&15
      float v = acc[t][r];
      if (cnt) v = (v + fcnt * bias[n]) * inv;
      if (do_relu) v = fmaxf(v, 0.f);
      if (OB) ((unsigned short*)OutV)[(size_t)m*ldo + n] = f2bf(v);
      else    ((float*)OutV)[(size_t)m*ldo + n] = v;
    }
  }
}

// ------- edge aggregation, layer 1 (dim 128, 2 ch/lane, 4 nodes/block, bf16, ILP4) ----
__global__ __launch_bounds__(256)
void k_edge1(const unsigned short* __restrict__ A, const unsigned short* __restrict__ Bm,
             const float* __restrict__ b1, const int* __restrict__ offs,
             const int* __restrict__ cnt, const int* __restrict__ ssrc,
             float* __restrict__ S)
{
  int v = blockIdx.x*4 + (threadIdx.x >> 6);
  int c = threadIdx.x & 63;  // channels 2c, 2c+1
  ushort2 a2 = *reinterpret_cast<const ushort2*>(&A[(size_t)v*GH + 2*c]);
  float2 bb = *reinterpret_cast<const float2*>(&b1[2*c]);
  float ax = bf2f(a2.x) + bb.x, ay = bf2f(a2.y) + bb.y;
  int beg = offs[v], n = cnt[v];
  float sx = 0.f, sy = 0.f;
  int i = 0;
  for (; i + 4 <= n; i += 4){
    int s0 = ssrc[beg + i], s1 = ssrc[beg + i + 1];
    int s2 = ssrc[beg + i + 2], s3 = ssrc[beg + i + 3];
    ushort2 b0 = *reinterpret_cast<const ushort2*>(&Bm[(size_t)s0*GH + 2*c]);
    ushort2 b1v= *reinterpret_cast<const ushort2*>(&Bm[(size_t)s1*GH + 2*c]);
    ushort2 b2 = *reinterpret_cast<const ushort2*>(&Bm[(size_t)s2*GH + 2*c]);
    ushort2 b3 = *reinterpret_cast<const ushort2*>(&Bm[(size_t)s3*GH + 2*c]);
    sx += fmaxf(ax + bf2f(b0.x), 0.f) + fmaxf(ax + bf2f(b1v.x), 0.f)
        + fmaxf(ax + bf2f(b2.x), 0.f) + fmaxf(ax + bf2f(b3.x), 0.f);
    sy += fmaxf(ay + bf2f(b0.y), 0.f) + fmaxf(ay + bf2f(b1v.y), 0.f)
        + fmaxf(ay + bf2f(b2.y), 0.f) + fmaxf(ay + bf2f(b3.y), 0.f);
  }
  for (; i < n; ++i){
    int s0 = ssrc[beg + i];
    ushort2 b0 = *reinterpret_cast<const ushort2*>(&Bm[(size_t)s0*GH + 2*c]);
    sx += fmaxf(ax + bf2f(b0.x), 0.f);
    sy += fmaxf(ay + bf2f(b0.y), 0.f);
  }
  *reinterpret_cast<float2*>(&S[(size_t)v*GH + 2*c]) = make_float2(sx, sy);
}

// ------- edge aggregation, layer 2 (dim 64, 1 ch/lane, 4 nodes/block, bf16, ILP4) -----
__global__ __launch_bounds__(256)
void k_edge2(const unsigned short* __restrict__ C, const unsigned short* __restrict__ D,
             const float* __restrict__ b1, const int* __restrict__ offs,
             const int* __restrict__ cnt, const int* __restrict__ ssrc,
             float* __restrict__ S2)
{
  int v = blockIdx.x*4 + (threadIdx.x >> 6);
  int c = threadIdx.x & 63;
  float a = bf2f(C[(size_t)v*GD + c]) + b1[c];
  int beg = offs[v], n = cnt[v];
  float s = 0.f;
  int i = 0;
  for (; i + 4 <= n; i += 4){
    int u0 = ssrc[beg + i], u1 = ssrc[beg + i + 1];
    int u2 = ssrc[beg + i + 2], u3 = ssrc[beg + i + 3];
    float d0 = bf2f(D[(size_t)u0*GD + c]);
    float d1 = bf2f(D[(size_t)u1*GD + c]);
    float d2 = bf2f(D[(size_t)u2*GD + c]);
    float d3 = bf2f(D[(size_t)u3*GD + c]);
    s += fmaxf(a + d0, 0.f) + fmaxf(a + d1, 0.f)
       + fmaxf(a + d2, 0.f) + fmaxf(a + d3, 0.f);
  }
  for (; i < n; ++i){
    int u0 = ssrc[beg + i];
    s += fmaxf(a + bf2f(D[(size_t)u0*GD + c]), 0.f);
  }
  S2[(size_t)v*GD + c] = s;
}

// ---------------- graph partial sums (atomic, node-parallel) ----------------
__global__ __launch_bounds__(256)
void k_gsum(const float* __restrict__ H2, const int* __restrict__ nb,
            float* __restrict__ gsum)
{
  int c = threadIdx.x & 63;
  int w = threadIdx.x >> 6;      // 0..3
  int base = blockIdx.x * GCH;
  int end = base + GCH; if (end > NN) end = NN;
  float acc = 0.f;
  int cur = -1;
  for (int i = base + w; i < end; i += 4){
    int g = nb[i];
    if (g != cur){
      if (cur >= 0) atomicAdd(&gsum[cur*GD + c], acc);
      cur = g; acc = 0.f;
    }
    acc += H2[(size_t)i*GD + c];
  }
  if (cur >= 0) atomicAdd(&gsum[cur*GD + c], acc);
}

// ---------------- actor head: one block per batch row (divide fused here) -----
__global__ __launch_bounds__(256)
void k_head(const float* __restrict__ state, const float* __restrict__ gsum,
            const int* __restrict__ nb,
            const float* __restrict__ fc1w, const float* __restrict__ fc1b,
            const float* __restrict__ fc2w, const float* __restrict__ fc2b,
            const float* __restrict__ mw, const float* __restrict__ mb,
            const float* __restrict__ lw, const float* __restrict__ lb,
            float* __restrict__ out)
{
  int b = blockIdx.x, t = threadIdx.x;
  __shared__ float z[SD + GD];
  __shared__ float h1[HID];
  __shared__ float h2[HID];
  __shared__ int bounds[2];
  if (t < 2){
    int target = b + t;
    int lo = 0, hi = NN;
    while (lo < hi){ int mid = (lo + hi) >> 1; if (nb[mid] < target) lo = mid + 1; else hi = mid; }
    bounds[t] = lo;
  }
  if (t < SD) z[t] = state[b*SD + t];
  __syncthreads();
  if (t >= SD && t < SD + GD){
    float n = (float)(bounds[1] - bounds[0]);
    z[t] = gsum[b*GD + (t - SD)] / fmaxf(n, 1.f);
  }
  __syncthreads();
  float acc = fc1b[t];
  for (int k = 0; k < SD + GD; ++k) acc = fmaf(z[k], fc1w[k*HID + t], acc);
  h1[t] = fmaxf(acc, 0.f);
  __syncthreads();
  acc = fc2b[t];
  for (int k = 0; k < HID; ++k) acc = fmaf(h1[k], fc2w[k*HID + t], acc);
  h2[t] = fmaxf(acc, 0.f);
  __syncthreads();
  if (t < AD){
    float m = mb[t];
    for (int k = 0; k < HID; ++k) m = fmaf(h2[k], mw[k*AD + t], m);
    out[b*AD + t] = m;
  } else if (t < 2*AD){
    int j = t - AD;
    float l = lb[j];
    for (int k = 0; k < HID; ++k) l = fmaf(h2[k], lw[k*AD + j], l);
    out[NB*AD + b*AD + j] = fminf(fmaxf(l, -20.f), 2.f);
  }
}

extern "C" void kernel_launch(void* const* d_in, const int* in_sizes, int n_in,
                              void* d_out, int out_size, void* d_ws, size_t ws_size,
                              hipStream_t stream)
{
  const float* state = (const float*)d_in[0];
  const float* x     = (const float*)d_in[1];
  const int*   eidx  = (const int*)  d_in[2];
  const int*   nb    = (const int*)  d_in[3];
  const float* g1w1  = (const float*)d_in[4];
  const float* g1b1  = (const float*)d_in[5];
  const float* g1w2  = (const float*)d_in[6];
  const float* g1b2  = (const float*)d_in[7];
  const float* g2w1  = (const float*)d_in[8];
  const float* g2b1  = (const float*)d_in[9];
  const float* g2w2  = (const float*)d_in[10];
  const float* g2b2  = (const float*)d_in[11];
  const float* fc1w  = (const float*)d_in[12];
  const float* fc1b  = (const float*)d_in[13];
  const float* fc2w  = (const float*)d_in[14];
  const float* fc2b  = (const float*)d_in[15];
  const float* mw    = (const float*)d_in[16];
  const float* mb    = (const float*)d_in[17];
  const float* lw    = (const float*)d_in[18];
  const float* lb    = (const float*)d_in[19];

  const int* e_src = eidx;        // edge_index[0]
  const int* e_dst = eidx + NE;   // edge_index[1]

  char* p = (char*)d_ws;
  auto alloc = [&](size_t bytes){ char* r = p; p += align256(bytes); return r; };
  int*   cnt    = (int*)  alloc((size_t)NN*4);
  int*   offs   = (int*)  alloc((size_t)NN*4);
  int*   rank   = (int*)  alloc((size_t)NE*4);
  int*   ssrc   = (int*)  alloc((size_t)NE*4);
  int*   bsum   = (int*)  alloc((size_t)SCB*4);
  int*   boff   = (int*)  alloc((size_t)SCB*4);
  float* gsum   = (float*)alloc((size_t)NB*GD*4);
  unsigned short* fA = (unsigned short*)alloc((size_t)NN*GH*2);   // bf16 [NN,128]
  unsigned short* fB = (unsigned short*)alloc((size_t)NN*GH*2);   // bf16 [NN,128]
  float* fS     = (float*)alloc((size_t)NN*GH*4);                 // fp32 [NN,128]
  float* fH     = (float*)alloc((size_t)NN*GH*4);                 // fp32 [NN,128]
  // overlays (lifetimes disjoint):
  unsigned short* fC = fA;                          // bf16 [NN,64]
  unsigned short* fD = fA + (size_t)NN*GD;          // bf16 [NN,64]
  float* fS2    = (float*)fB;                       // fp32 [NN,64] (fits: NN*GH*2 bytes)
  float* fH2    = fS;                               // fp32 [NN,64]

  hipMemsetAsync(cnt, 0, (size_t)NN*4, stream);
  hipMemsetAsync(gsum, 0, (size_t)NB*GD*4, stream);

  dim3 b256(256);
  const int EB = (NE + 1023)/1024;   // 782
  k_hist  <<<dim3(EB), b256, 0, stream>>>(e_dst, cnt, rank);
  k_scan_a<<<dim3(SCB), b256, 0, stream>>>(cnt, bsum);
  k_scan_b<<<dim3(1),   b256, 0, stream>>>(bsum, boff);
  k_scan_c<<<dim3(SCB), b256, 0, stream>>>(cnt, boff, offs);
  k_place <<<dim3(EB), b256, 0, stream>>>(e_src, e_dst, offs, rank, ssrc);

  const int MB = (NN + 63)/64;  // 782
  // Layer 1: fA = x @ w1[0:64,:], fB = x @ w1[64:128,:]  (bf16 out, z-fused)
  k_mgemm<1><<<dim3(MB,2,2), b256, 0, stream>>>(x, g1w1, fA, g1w1 + 64*GH, fB,
                                                NN, 64, GH, GH, nullptr, nullptr, 0);
  k_edge1<<<dim3(NN/4), b256, 0, stream>>>(fA, fB, g1b1, offs, cnt, ssrc, fS);
  // h = relu((S @ w2 + cnt*b2)/max(cnt,1))  (fp32 out)
  k_mgemm<0><<<dim3(MB,2,1), b256, 0, stream>>>(fS, g1w2, fH, g1w2, fH,
                                                NN, 128, GH, GH, cnt, g1b2, 1);

  // Layer 2: fC = h @ w1[0:128,:], fD = h @ w1[128:256,:]  (bf16 out, z-fused)
  k_mgemm<1><<<dim3(MB,1,2), b256, 0, stream>>>(fH, g2w1, fC, g2w1 + 128*GD, fD,
                                                NN, 128, GD, GD, nullptr, nullptr, 0);
  k_edge2<<<dim3(NN/4), b256, 0, stream>>>(fC, fD, g2b1, offs, cnt, ssrc, fS2);
  // h2 = (S2 @ w2 + cnt*b2)/max(cnt,1)   (no relu, fp32 out)
  k_mgemm<0><<<dim3(MB,1,1), b256, 0, stream>>>(fS2, g2w2, fH2, g2w2, fH2,
                                                NN, 64, GD, GD, cnt, g2b2, 0);

  k_gsum<<<dim3((NN+GCH-1)/GCH), b256, 0, stream>>>(fH2, nb, gsum);
  k_head<<<dim3(NB), b256, 0, stream>>>(state, gsum, nb, fc1w, fc1b, fc2w, fc2b,
                                        mw, mb, lw, lb, (float*)d_out);
}

// Round 6
// 321.871 us; speedup vs baseline: 2.0071x; 1.1144x over previous
//
#include <hip/hip_runtime.h>

#define NN 50000      // nodes
#define NE 800000     // edges
#define NB 128        // graphs / batch
#define SD 64         // state dim / node dim
#define GH 128        // gnn layer1 width
#define GD 64         // gnn layer2 width
#define HID 256       // actor hidden
#define AD 8          // action dim
#define SCB 196       // scan blocks: 196*256 = 50176 >= NN
#define GCH 128       // nodes per k_gsum chunk

static inline size_t align256(size_t x){ return (x + 255) & ~size_t(255); }

typedef __attribute__((ext_vector_type(8))) short short8v;
typedef __attribute__((ext_vector_type(4))) float f32x4;

__device__ inline unsigned short f2bf(float f){  // RNE
  unsigned u = __builtin_bit_cast(unsigned, f);
  return (unsigned short)((u + 0x7FFFu + ((u >> 16) & 1u)) >> 16);
}
__device__ inline float bf2f(unsigned short h){
  return __builtin_bit_cast(float, ((unsigned)h) << 16);
}

// ---------------- CSR build (rank trick, ILP8) ----------------
__global__ void k_hist(const int* __restrict__ dst, int* __restrict__ cnt,
                       int* __restrict__ rank){
  int e = blockIdx.x*2048 + threadIdx.x;
  #pragma unroll
  for (int j = 0; j < 8; ++j){
    int ee = e + j*256;
    if (ee < NE) rank[ee] = atomicAdd(&cnt[dst[ee]], 1);
  }
}

__global__ __launch_bounds__(256)
void k_scan_a(const int* __restrict__ cnt, int* __restrict__ bsum){
  __shared__ int sm[256];
  int t = threadIdx.x;
  int i = blockIdx.x*256 + t;
  int v = (i < NN) ? cnt[i] : 0;
  sm[t] = v; __syncthreads();
  for (int d = 128; d > 0; d >>= 1){
    if (t < d) sm[t] += sm[t + d];
    __syncthreads();
  }
  if (t == 0) bsum[blockIdx.x] = sm[0];
}

__global__ __launch_bounds__(256)
void k_scan_b(const int* __restrict__ bsum, int* __restrict__ boff){
  __shared__ int sm[256];
  int t = threadIdx.x;
  int v = (t < SCB) ? bsum[t] : 0;
  sm[t] = v; __syncthreads();
  for (int d = 1; d < 256; d <<= 1){
    int add = (t >= d) ? sm[t - d] : 0;
    __syncthreads();
    sm[t] += add;
    __syncthreads();
  }
  if (t < SCB) boff[t] = sm[t] - v;   // exclusive
}

__global__ __launch_bounds__(256)
void k_scan_c(const int* __restrict__ cnt, const int* __restrict__ boff,
              int* __restrict__ offs){
  __shared__ int sm[256];
  int t = threadIdx.x;
  int i = blockIdx.x*256 + t;
  int v = (i < NN) ? cnt[i] : 0;
  sm[t] = v; __syncthreads();
  for (int d = 1; d < 256; d <<= 1){
    int add = (t >= d) ? sm[t - d] : 0;
    __syncthreads();
    sm[t] += add;
    __syncthreads();
  }
  if (i < NN) offs[i] = sm[t] - v + boff[blockIdx.x];
}

__global__ void k_place(const int* __restrict__ esrc, const int* __restrict__ edst,
                        const int* __restrict__ offs, const int* __restrict__ rank,
                        int* __restrict__ ssrc){
  int e = blockIdx.x*2048 + threadIdx.x;
  #pragma unroll
  for (int j = 0; j < 8; ++j){
    int ee = e + j*256;
    if (ee < NE) ssrc[offs[edst[ee]] + rank[ee]] = esrc[ee];
  }
}

// ---------------- single-pass bf16 MFMA GEMM (z-fused pairs) ----------------
// z = blockIdx.z selects (W0,Out0) or (W1,Out1). In: fp32 (IB=0) or bf16 (IB=1).
// post: if cnt: v=(v+cnt[m]*bias[n])/max(cnt[m],1); if relu: max(v,0)
// OB: 0 -> fp32 out, 1 -> bf16(RNE) out
template<int IB, int OB>
__global__ __launch_bounds__(256)
void k_mgemm(const void* __restrict__ In,
             const float* __restrict__ W0, void* __restrict__ Out0,
             const float* __restrict__ W1, void* __restrict__ Out1,
             int M, int K, int ldw, int ldo,
             const int* __restrict__ cnt, const float* __restrict__ bias,
             int do_relu)
{
  const float* W = (blockIdx.z == 0) ? W0 : W1;
  void* OutV     = (blockIdx.z == 0) ? Out0 : Out1;
  __shared__ short Ah[64*40], Bh[64*40];
  int tid = threadIdx.x;
  int w = tid >> 6, lane = tid & 63, l15 = tid & 15, quad = lane >> 4;
  int m0 = blockIdx.x*64, n0 = blockIdx.y*64;
  f32x4 acc[4];
  #pragma unroll
  for (int t = 0; t < 4; ++t) acc[t] = (f32x4){0.f,0.f,0.f,0.f};

  for (int k0 = 0; k0 < K; k0 += 32){
    // stage A tile [64 rows x 32 k] bf16, layout [m][k]
    if (IB){
      int m = tid >> 2, o = tid & 3;       // 256 slots of 8 bf16
      const unsigned short* In16 = (const unsigned short*)In;
      short8v v = (short8v)(short)0;
      if (m0 + m < M)
        v = *reinterpret_cast<const short8v*>(&In16[(size_t)(m0+m)*K + k0 + o*8]);
      *reinterpret_cast<short8v*>(&Ah[m*40 + o*8]) = v;
    } else {
      const float* InF = (const float*)In;
      #pragma unroll
      for (int i = 0; i < 2; ++i){
        int s = tid + i*256;        // 0..511 float4 slots
        int m = s >> 3, q = s & 7;  // row, k-quad
        float4 v = make_float4(0.f,0.f,0.f,0.f);
        if (m0 + m < M) v = *reinterpret_cast<const float4*>(&InF[(size_t)(m0+m)*K + k0 + q*4]);
        short4 h4;
        h4.x = (short)f2bf(v.x); h4.y = (short)f2bf(v.y);
        h4.z = (short)f2bf(v.z); h4.w = (short)f2bf(v.w);
        *reinterpret_cast<short4*>(&Ah[m*40 + q*4]) = h4;
      }
    }
    // stage B tile [32 k x 64 n] fp32 -> bf16, transposed to [n][k]
    #pragma unroll
    for (int i = 0; i < 2; ++i){
      int s = tid + i*256;          // 0..511
      int r = s >> 4, cq = s & 15;  // k-row, col-quad
      float4 v = *reinterpret_cast<const float4*>(&W[(size_t)(k0+r)*ldw + n0 + cq*4]);
      #pragma unroll
      for (int j = 0; j < 4; ++j)
        Bh[(cq*4+j)*40 + r] = (short)f2bf((&v.x)[j]);
    }
    __syncthreads();
    short8v ah = *reinterpret_cast<short8v*>(&Ah[(w*16 + l15)*40 + quad*8]);
    #pragma unroll
    for (int t = 0; t < 4; ++t){
      short8v bh = *reinterpret_cast<short8v*>(&Bh[(t*16 + l15)*40 + quad*8]);
      acc[t] = __builtin_amdgcn_mfma_f32_16x16x32_bf16(ah, bh, acc[t], 0, 0, 0);
    }
    __syncthreads();
  }
  #pragma unroll
  for (int r = 0; r < 4; ++r){
    int m = m0 + w*16 + quad*4 + r;   // C/D row = quad*4 + reg
    if (m >= M) continue;
    float fcnt = 0.f, inv = 1.f;
    if (cnt){ fcnt = (float)cnt[m]; inv = 1.f / fmaxf(fcnt, 1.f); }
    #pragma unroll
    for (int t = 0; t < 4; ++t){
      int n = n0 + t*16 + l15;        // C/D col = lane&15
      float v = acc[t][r];
      if (cnt) v = (v + fcnt * bias[n]) * inv;
      if (do_relu) v = fmaxf(v, 0.f);
      if (OB) ((unsigned short*)OutV)[(size_t)m*ldo + n] = f2bf(v);
      else    ((float*)OutV)[(size_t)m*ldo + n] = v;
    }
  }
}

// ------- edge aggregation, layer 1 (dim 128, 2 ch/lane, 4 nodes/block, bf16, ILP8) ----
__global__ __launch_bounds__(256)
void k_edge1(const unsigned short* __restrict__ A, const unsigned short* __restrict__ Bm,
             const float* __restrict__ b1, const int* __restrict__ offs,
             const int* __restrict__ cnt, const int* __restrict__ ssrc,
             unsigned short* __restrict__ S)
{
  int v = blockIdx.x*4 + (threadIdx.x >> 6);
  int c = threadIdx.x & 63;  // channels 2c, 2c+1
  int beg = offs[v], n = cnt[v];
  float sx = 0.f, sy = 0.f;
  if (n > 0){
    ushort2 a2 = *reinterpret_cast<const ushort2*>(&A[(size_t)v*GH + 2*c]);
    float2 bb = *reinterpret_cast<const float2*>(&b1[2*c]);
    float ax = bf2f(a2.x) + bb.x, ay = bf2f(a2.y) + bb.y;
    for (int i = 0; i < n; i += 8){
      int ss[8];
      #pragma unroll
      for (int j = 0; j < 8; ++j)
        ss[j] = (i + j < n) ? ssrc[beg + i + j] : ssrc[beg];
      ushort2 bv[8];
      #pragma unroll
      for (int j = 0; j < 8; ++j)
        bv[j] = *reinterpret_cast<const ushort2*>(&Bm[(size_t)ss[j]*GH + 2*c]);
      #pragma unroll
      for (int j = 0; j < 8; ++j){
        float live = (i + j < n) ? 1.f : 0.f;
        sx += live * fmaxf(ax + bf2f(bv[j].x), 0.f);
        sy += live * fmaxf(ay + bf2f(bv[j].y), 0.f);
      }
    }
  }
  ushort2 o; o.x = f2bf(sx); o.y = f2bf(sy);
  *reinterpret_cast<ushort2*>(&S[(size_t)v*GH + 2*c]) = o;
}

// ------- edge aggregation, layer 2 (dim 64, 1 ch/lane, 4 nodes/block, bf16, ILP8) -----
__global__ __launch_bounds__(256)
void k_edge2(const unsigned short* __restrict__ C, const unsigned short* __restrict__ D,
             const float* __restrict__ b1, const int* __restrict__ offs,
             const int* __restrict__ cnt, const int* __restrict__ ssrc,
             unsigned short* __restrict__ S2)
{
  int v = blockIdx.x*4 + (threadIdx.x >> 6);
  int c = threadIdx.x & 63;
  int beg = offs[v], n = cnt[v];
  float s = 0.f;
  if (n > 0){
    float a = bf2f(C[(size_t)v*GD + c]) + b1[c];
    for (int i = 0; i < n; i += 8){
      int ss[8];
      #pragma unroll
      for (int j = 0; j < 8; ++j)
        ss[j] = (i + j < n) ? ssrc[beg + i + j] : ssrc[beg];
      float dv[8];
      #pragma unroll
      for (int j = 0; j < 8; ++j)
        dv[j] = bf2f(D[(size_t)ss[j]*GD + c]);
      #pragma unroll
      for (int j = 0; j < 8; ++j){
        float live = (i + j < n) ? 1.f : 0.f;
        s += live * fmaxf(a + dv[j], 0.f);
      }
    }
  }
  S2[(size_t)v*GD + c] = f2bf(s);
}

// ---------------- graph partial sums (atomic, node-parallel) ----------------
__global__ __launch_bounds__(256)
void k_gsum(const float* __restrict__ H2, const int* __restrict__ nb,
            float* __restrict__ gsum)
{
  int c = threadIdx.x & 63;
  int w = threadIdx.x >> 6;      // 0..3
  int base = blockIdx.x * GCH;
  int end = base + GCH; if (end > NN) end = NN;
  float acc = 0.f;
  int cur = -1;
  for (int i = base + w; i < end; i += 4){
    int g = nb[i];
    if (g != cur){
      if (cur >= 0) atomicAdd(&gsum[cur*GD + c], acc);
      cur = g; acc = 0.f;
    }
    acc += H2[(size_t)i*GD + c];
  }
  if (cur >= 0) atomicAdd(&gsum[cur*GD + c], acc);
}

// ---------------- actor head: one block per batch row (divide fused here) -----
__global__ __launch_bounds__(256)
void k_head(const float* __restrict__ state, const float* __restrict__ gsum,
            const int* __restrict__ nb,
            const float* __restrict__ fc1w, const float* __restrict__ fc1b,
            const float* __restrict__ fc2w, const float* __restrict__ fc2b,
            const float* __restrict__ mw, const float* __restrict__ mb,
            const float* __restrict__ lw, const float* __restrict__ lb,
            float* __restrict__ out)
{
  int b = blockIdx.x, t = threadIdx.x;
  __shared__ float z[SD + GD];
  __shared__ float h1[HID];
  __shared__ float h2[HID];
  __shared__ int bounds[2];
  if (t < 2){
    int target = b + t;
    int lo = 0, hi = NN;
    while (lo < hi){ int mid = (lo + hi) >> 1; if (nb[mid] < target) lo = mid + 1; else hi = mid; }
    bounds[t] = lo;
  }
  if (t < SD) z[t] = state[b*SD + t];
  __syncthreads();
  if (t >= SD && t < SD + GD){
    float n = (float)(bounds[1] - bounds[0]);
    z[t] = gsum[b*GD + (t - SD)] / fmaxf(n, 1.f);
  }
  __syncthreads();
  float acc = fc1b[t];
  for (int k = 0; k < SD + GD; ++k) acc = fmaf(z[k], fc1w[k*HID + t], acc);
  h1[t] = fmaxf(acc, 0.f);
  __syncthreads();
  acc = fc2b[t];
  for (int k = 0; k < HID; ++k) acc = fmaf(h1[k], fc2w[k*HID + t], acc);
  h2[t] = fmaxf(acc, 0.f);
  __syncthreads();
  if (t < AD){
    float m = mb[t];
    for (int k = 0; k < HID; ++k) m = fmaf(h2[k], mw[k*AD + t], m);
    out[b*AD + t] = m;
  } else if (t < 2*AD){
    int j = t - AD;
    float l = lb[j];
    for (int k = 0; k < HID; ++k) l = fmaf(h2[k], lw[k*AD + j], l);
    out[NB*AD + b*AD + j] = fminf(fmaxf(l, -20.f), 2.f);
  }
}

extern "C" void kernel_launch(void* const* d_in, const int* in_sizes, int n_in,
                              void* d_out, int out_size, void* d_ws, size_t ws_size,
                              hipStream_t stream)
{
  const float* state = (const float*)d_in[0];
  const float* x     = (const float*)d_in[1];
  const int*   eidx  = (const int*)  d_in[2];
  const int*   nb    = (const int*)  d_in[3];
  const float* g1w1  = (const float*)d_in[4];
  const float* g1b1  = (const float*)d_in[5];
  const float* g1w2  = (const float*)d_in[6];
  const float* g1b2  = (const float*)d_in[7];
  const float* g2w1  = (const float*)d_in[8];
  const float* g2b1  = (const float*)d_in[9];
  const float* g2w2  = (const float*)d_in[10];
  const float* g2b2  = (const float*)d_in[11];
  const float* fc1w  = (const float*)d_in[12];
  const float* fc1b  = (const float*)d_in[13];
  const float* fc2w  = (const float*)d_in[14];
  const float* fc2b  = (const float*)d_in[15];
  const float* mw    = (const float*)d_in[16];
  const float* mb    = (const float*)d_in[17];
  const float* lw    = (const float*)d_in[18];
  const float* lb    = (const float*)d_in[19];

  const int* e_src = eidx;        // edge_index[0]
  const int* e_dst = eidx + NE;   // edge_index[1]

  char* p = (char*)d_ws;
  auto alloc = [&](size_t bytes){ char* r = p; p += align256(bytes); return r; };
  int*   cnt    = (int*)  alloc((size_t)NN*4);
  int*   offs   = (int*)  alloc((size_t)NN*4);
  int*   rank   = (int*)  alloc((size_t)NE*4);
  int*   ssrc   = (int*)  alloc((size_t)NE*4);
  int*   bsum   = (int*)  alloc((size_t)SCB*4);
  int*   boff   = (int*)  alloc((size_t)SCB*4);
  float* gsum   = (float*)alloc((size_t)NB*GD*4);
  unsigned short* fA = (unsigned short*)alloc((size_t)NN*GH*2);   // bf16 [NN,128]
  unsigned short* fB = (unsigned short*)alloc((size_t)NN*GH*2);   // bf16 [NN,128]
  unsigned short* fS = (unsigned short*)alloc((size_t)NN*GH*2);   // bf16 [NN,128]
  unsigned short* fH = (unsigned short*)alloc((size_t)NN*GH*2);   // bf16 [NN,128]
  // overlays (lifetimes disjoint):
  unsigned short* fC = fA;                          // bf16 [NN,64]
  unsigned short* fD = fA + (size_t)NN*GD;          // bf16 [NN,64]
  unsigned short* fS2= fB;                          // bf16 [NN,64]
  float* fH2    = (float*)fS;                       // fp32 [NN,64] (12.8MB fits NN*GH*2)

  hipMemsetAsync(cnt, 0, (size_t)NN*4, stream);
  hipMemsetAsync(gsum, 0, (size_t)NB*GD*4, stream);

  dim3 b256(256);
  const int EB = (NE + 2047)/2048;   // 391
  k_hist  <<<dim3(EB), b256, 0, stream>>>(e_dst, cnt, rank);
  k_scan_a<<<dim3(SCB), b256, 0, stream>>>(cnt, bsum);
  k_scan_b<<<dim3(1),   b256, 0, stream>>>(bsum, boff);
  k_scan_c<<<dim3(SCB), b256, 0, stream>>>(cnt, boff, offs);
  k_place <<<dim3(EB), b256, 0, stream>>>(e_src, e_dst, offs, rank, ssrc);

  const int MB = (NN + 63)/64;  // 782
  // Layer 1: fA = x @ w1[0:64,:], fB = x @ w1[64:128,:]  (fp32 in, bf16 out, z-fused)
  k_mgemm<0,1><<<dim3(MB,2,2), b256, 0, stream>>>(x, g1w1, fA, g1w1 + 64*GH, fB,
                                                  NN, 64, GH, GH, nullptr, nullptr, 0);
  k_edge1<<<dim3(NN/4), b256, 0, stream>>>(fA, fB, g1b1, offs, cnt, ssrc, fS);
  // fH = relu((fS @ w2 + cnt*b2)/max(cnt,1))  (bf16 in, bf16 out)
  k_mgemm<1,1><<<dim3(MB,2,1), b256, 0, stream>>>(fS, g1w2, fH, g1w2, fH,
                                                  NN, 128, GH, GH, cnt, g1b2, 1);

  // Layer 2: fC = fH @ w1[0:128,:], fD = fH @ w1[128:256,:]  (bf16 in, bf16 out, z-fused)
  k_mgemm<1,1><<<dim3(MB,1,2), b256, 0, stream>>>(fH, g2w1, fC, g2w1 + 128*GD, fD,
                                                  NN, 128, GD, GD, nullptr, nullptr, 0);
  k_edge2<<<dim3(NN/4), b256, 0, stream>>>(fC, fD, g2b1, offs, cnt, ssrc, fS2);
  // fH2 = (fS2 @ w2 + cnt*b2)/max(cnt,1)   (bf16 in, fp32 out, no relu)
  k_mgemm<1,0><<<dim3(MB,1,1), b256, 0, stream>>>(fS2, g2w2, fH2, g2w2, fH2,
                                                  NN, 64, GD, GD, cnt, g2b2, 0);

  k_gsum<<<dim3((NN+GCH-1)/GCH), b256, 0, stream>>>(fH2, nb, gsum);
  k_head<<<dim3(NB), b256, 0, stream>>>(state, gsum, nb, fc1w, fc1b, fc2w, fc2b,
                                        mw, mb, lw, lb, (float*)d_out);
}

// Round 7
// 314.018 us; speedup vs baseline: 2.0573x; 1.0250x over previous
//
#include <hip/hip_runtime.h>

#define NN 50000      // nodes
#define NE 800000     // edges
#define NB 128        // graphs / batch
#define SD 64         // state dim / node dim
#define GH 128        // gnn layer1 width
#define GD 64         // gnn layer2 width
#define HID 256       // actor hidden
#define AD 8          // action dim
#define SCB 196       // scan blocks: 196*256 = 50176 >= NN

static inline size_t align256(size_t x){ return (x + 255) & ~size_t(255); }

typedef __attribute__((ext_vector_type(8))) short short8v;
typedef __attribute__((ext_vector_type(4))) float f32x4;

__device__ inline unsigned short f2bf(float f){  // RNE
  unsigned u = __builtin_bit_cast(unsigned, f);
  return (unsigned short)((u + 0x7FFFu + ((u >> 16) & 1u)) >> 16);
}
__device__ inline float bf2f(unsigned short h){
  return __builtin_bit_cast(float, ((unsigned)h) << 16);
}

// ---------------- prep: cast x + weights to bf16 ----------------
__global__ __launch_bounds__(256)
void k_prep(const float* __restrict__ x,
            const float* __restrict__ w1, const float* __restrict__ w2,
            const float* __restrict__ w3, const float* __restrict__ w4,
            unsigned short* __restrict__ xb, unsigned short* __restrict__ wb)
{
  const int S0 = NN*SD/4;                 // 800000 float4 slots for x
  const int T  = S0 + 4096 + 4096 + 4096 + 1024;
  for (int s = blockIdx.x*256 + threadIdx.x; s < T; s += gridDim.x*256){
    const float* src; unsigned short* dst; int loc;
    if (s < S0){ src = x; dst = xb; loc = s; }
    else {
      int t = s - S0;
      if      (t < 4096){ src = w1; dst = wb;         loc = t; }
      else if (t < 8192){ src = w2; dst = wb + 16384; loc = t - 4096; }
      else if (t < 12288){ src = w3; dst = wb + 32768; loc = t - 8192; }
      else               { src = w4; dst = wb + 49152; loc = t - 12288; }
    }
    float4 v = reinterpret_cast<const float4*>(src)[loc];
    ushort4 o; o.x = f2bf(v.x); o.y = f2bf(v.y); o.z = f2bf(v.z); o.w = f2bf(v.w);
    reinterpret_cast<ushort4*>(dst)[loc] = o;
  }
}

// ---------------- CSR build (rank trick, ILP8) ----------------
__global__ void k_hist(const int* __restrict__ dst, int* __restrict__ cnt,
                       int* __restrict__ rank){
  int e = blockIdx.x*2048 + threadIdx.x;
  #pragma unroll
  for (int j = 0; j < 8; ++j){
    int ee = e + j*256;
    if (ee < NE) rank[ee] = atomicAdd(&cnt[dst[ee]], 1);
  }
}

__global__ __launch_bounds__(256)
void k_scan_a(const int* __restrict__ cnt, int* __restrict__ bsum){
  __shared__ int sm[256];
  int t = threadIdx.x;
  int i = blockIdx.x*256 + t;
  int v = (i < NN) ? cnt[i] : 0;
  sm[t] = v; __syncthreads();
  for (int d = 128; d > 0; d >>= 1){
    if (t < d) sm[t] += sm[t + d];
    __syncthreads();
  }
  if (t == 0) bsum[blockIdx.x] = sm[0];
}

__global__ __launch_bounds__(256)
void k_scan_b(const int* __restrict__ bsum, int* __restrict__ boff){
  __shared__ int sm[256];
  int t = threadIdx.x;
  int v = (t < SCB) ? bsum[t] : 0;
  sm[t] = v; __syncthreads();
  for (int d = 1; d < 256; d <<= 1){
    int add = (t >= d) ? sm[t - d] : 0;
    __syncthreads();
    sm[t] += add;
    __syncthreads();
  }
  if (t < SCB) boff[t] = sm[t] - v;   // exclusive
}

__global__ __launch_bounds__(256)
void k_scan_c(const int* __restrict__ cnt, const int* __restrict__ boff,
              int* __restrict__ offs){
  __shared__ int sm[256];
  int t = threadIdx.x;
  int i = blockIdx.x*256 + t;
  int v = (i < NN) ? cnt[i] : 0;
  sm[t] = v; __syncthreads();
  for (int d = 1; d < 256; d <<= 1){
    int add = (t >= d) ? sm[t - d] : 0;
    __syncthreads();
    sm[t] += add;
    __syncthreads();
  }
  if (i < NN) offs[i] = sm[t] - v + boff[blockIdx.x];
}

__global__ void k_place(const int* __restrict__ esrc, const int* __restrict__ edst,
                        const int* __restrict__ offs, const int* __restrict__ rank,
                        int* __restrict__ ssrc){
  int e = blockIdx.x*2048 + threadIdx.x;
  #pragma unroll
  for (int j = 0; j < 8; ++j){
    int ee = e + j*256;
    if (ee < NE) ssrc[offs[edst[ee]] + rank[ee]] = esrc[ee];
  }
}

// ---------------- all-bf16 MFMA GEMM (z-fused pairs) ----------------
// In bf16 [M,K]; W bf16 [K,ldw]; z selects (W0,Out0)/(W1,Out1).
// post: if cnt: v=(v+cnt[m]*bias[n])/max(cnt[m],1); if relu: max(v,0)
// GS=1: graph-sum epilogue (atomicAdd into gsum by nb[m]); Out unused.
template<int OB, int GS>
__global__ __launch_bounds__(256)
void k_mgemm(const unsigned short* __restrict__ In,
             const unsigned short* __restrict__ W0, void* __restrict__ Out0,
             const unsigned short* __restrict__ W1, void* __restrict__ Out1,
             int M, int K, int ldw, int ldo,
             const int* __restrict__ cnt, const float* __restrict__ bias,
             int do_relu, const int* __restrict__ nb, float* __restrict__ gsum)
{
  const unsigned short* W = (blockIdx.z == 0) ? W0 : W1;
  void* OutV = (blockIdx.z == 0) ? Out0 : Out1;
  __shared__ short Ah[64*40], Bh[64*40];
  int tid = threadIdx.x;
  int w = tid >> 6, lane = tid & 63, l15 = tid & 15, quad = lane >> 4;
  int m0 = blockIdx.x*64, n0 = blockIdx.y*64;
  f32x4 acc[4];
  #pragma unroll
  for (int t = 0; t < 4; ++t) acc[t] = (f32x4){0.f,0.f,0.f,0.f};

  for (int k0 = 0; k0 < K; k0 += 32){
    { int m = tid >> 2, o = tid & 3;   // A: [64 rows][32 k], short8 copies
      short8v v = (short8v)(short)0;
      if (m0 + m < M)
        v = *reinterpret_cast<const short8v*>(&In[(size_t)(m0+m)*K + k0 + o*8]);
      *reinterpret_cast<short8v*>(&Ah[m*40 + o*8]) = v;
    }
    { int r = tid >> 3, cq = tid & 7;  // B: [32 k][64 n] -> [n][k]
      short8v wv = *reinterpret_cast<const short8v*>(&W[(size_t)(k0+r)*ldw + n0 + cq*8]);
      #pragma unroll
      for (int j = 0; j < 8; ++j) Bh[(cq*8+j)*40 + r] = wv[j];
    }
    __syncthreads();
    short8v ah = *reinterpret_cast<short8v*>(&Ah[(w*16 + l15)*40 + quad*8]);
    #pragma unroll
    for (int t = 0; t < 4; ++t){
      short8v bh = *reinterpret_cast<short8v*>(&Bh[(t*16 + l15)*40 + quad*8]);
      acc[t] = __builtin_amdgcn_mfma_f32_16x16x32_bf16(ah, bh, acc[t], 0, 0, 0);
    }
    __syncthreads();
  }

  if constexpr (GS){
    __shared__ float Ts[64*65];
    #pragma unroll
    for (int r = 0; r < 4; ++r){
      int ml = w*16 + quad*4 + r;
      int m = m0 + ml;
      float fcnt = 0.f, inv = 1.f;
      if (m < M){ fcnt = (float)cnt[m]; inv = 1.f / fmaxf(fcnt, 1.f); }
      #pragma unroll
      for (int t = 0; t < 4; ++t){
        int n = t*16 + l15;
        Ts[ml*65 + n] = (acc[t][r] + fcnt * bias[n]) * inv;
      }
    }
    __syncthreads();
    int col = tid & 63, rg = tid >> 6;
    float a = 0.f; int cur = -1;
    for (int rr = rg*16; rr < rg*16 + 16; ++rr){
      int m = m0 + rr; if (m >= M) break;
      int g = nb[m];
      if (g != cur){ if (cur >= 0) atomicAdd(&gsum[cur*GD + col], a); cur = g; a = 0.f; }
      a += Ts[rr*65 + col];
    }
    if (cur >= 0) atomicAdd(&gsum[cur*GD + col], a);
  } else {
    #pragma unroll
    for (int r = 0; r < 4; ++r){
      int m = m0 + w*16 + quad*4 + r;
      if (m >= M) continue;
      float fcnt = 0.f, inv = 1.f;
      if (cnt){ fcnt = (float)cnt[m]; inv = 1.f / fmaxf(fcnt, 1.f); }
      #pragma unroll
      for (int t = 0; t < 4; ++t){
        int n = n0 + t*16 + l15;
        float v = acc[t][r];
        if (cnt) v = (v + fcnt * bias[n]) * inv;
        if (do_relu) v = fmaxf(v, 0.f);
        if (OB) ((unsigned short*)OutV)[(size_t)m*ldo + n] = f2bf(v);
        else    ((float*)OutV)[(size_t)m*ldo + n] = v;
      }
    }
  }
}

// ---------------- fused GNN-layer MLP: h = relu(mean(fS@W2)); C|D = h@W3 -------
__global__ __launch_bounds__(256)
void k_mlp2(const unsigned short* __restrict__ In,   // fS [NN,128] bf16
            const unsigned short* __restrict__ W2,   // [128,128] bf16
            const unsigned short* __restrict__ W3,   // [256,64] bf16
            const int* __restrict__ cnt, const float* __restrict__ b2,
            unsigned short* __restrict__ fC, unsigned short* __restrict__ fD)
{
  __shared__ short Ah[64*40];
  __shared__ short Bh[128*40];
  __shared__ unsigned short Hs[64*136];
  int tid = threadIdx.x;
  int w = tid >> 6, lane = tid & 63, l15 = tid & 15, quad = lane >> 4;
  int m0 = blockIdx.x*64;

  f32x4 acc[8];
  #pragma unroll
  for (int t = 0; t < 8; ++t) acc[t] = (f32x4){0.f,0.f,0.f,0.f};

  // ---- stage 1: h = fS @ W2 (64 rows x 128 cols) ----
  for (int k0 = 0; k0 < 128; k0 += 32){
    { int m = tid >> 2, o = tid & 3;
      short8v v = (short8v)(short)0;
      if (m0 + m < NN)
        v = *reinterpret_cast<const short8v*>(&In[(size_t)(m0+m)*GH + k0 + o*8]);
      *reinterpret_cast<short8v*>(&Ah[m*40 + o*8]) = v;
    }
    #pragma unroll
    for (int i = 0; i < 2; ++i){
      int s = tid + i*256; int r = s >> 4, cq = s & 15;
      short8v wv = *reinterpret_cast<const short8v*>(&W2[(size_t)(k0+r)*GH + cq*8]);
      #pragma unroll
      for (int j = 0; j < 8; ++j) Bh[(cq*8+j)*40 + r] = wv[j];
    }
    __syncthreads();
    short8v ah = *reinterpret_cast<short8v*>(&Ah[(w*16 + l15)*40 + quad*8]);
    #pragma unroll
    for (int t = 0; t < 8; ++t){
      short8v bh = *reinterpret_cast<short8v*>(&Bh[(t*16 + l15)*40 + quad*8]);
      acc[t] = __builtin_amdgcn_mfma_f32_16x16x32_bf16(ah, bh, acc[t], 0, 0, 0);
    }
    __syncthreads();
  }
  // epilogue 1: mean + bias + relu -> Hs (bf16)
  #pragma unroll
  for (int r = 0; r < 4; ++r){
    int ml = w*16 + quad*4 + r;
    int m = m0 + ml;
    float fcnt = 0.f, inv = 1.f;
    if (m < NN){ fcnt = (float)cnt[m]; inv = 1.f / fmaxf(fcnt, 1.f); }
    #pragma unroll
    for (int t = 0; t < 8; ++t){
      int col = t*16 + l15;
      float v = (acc[t][r] + fcnt * b2[col]) * inv;
      Hs[ml*136 + col] = f2bf(fmaxf(v, 0.f));
    }
  }
  __syncthreads();

  // ---- stage 2: C|D = h @ W3 halves (64 rows x 128 cols) ----
  f32x4 acc2[8];
  #pragma unroll
  for (int t = 0; t < 8; ++t) acc2[t] = (f32x4){0.f,0.f,0.f,0.f};
  for (int k0 = 0; k0 < 128; k0 += 32){
    #pragma unroll
    for (int i = 0; i < 2; ++i){
      int s = tid + i*256; int r = s >> 4, cq = s & 15;
      short8v wv;
      if (cq < 8) wv = *reinterpret_cast<const short8v*>(&W3[(size_t)(k0+r)*GD + cq*8]);
      else        wv = *reinterpret_cast<const short8v*>(&W3[(size_t)(128+k0+r)*GD + (cq-8)*8]);
      #pragma unroll
      for (int j = 0; j < 8; ++j) Bh[(cq*8+j)*40 + r] = wv[j];
    }
    __syncthreads();
    short8v ah = *reinterpret_cast<short8v*>(&Hs[(w*16 + l15)*136 + k0 + quad*8]);
    #pragma unroll
    for (int t = 0; t < 8; ++t){
      short8v bh = *reinterpret_cast<short8v*>(&Bh[(t*16 + l15)*40 + quad*8]);
      acc2[t] = __builtin_amdgcn_mfma_f32_16x16x32_bf16(ah, bh, acc2[t], 0, 0, 0);
    }
    __syncthreads();
  }
  #pragma unroll
  for (int r = 0; r < 4; ++r){
    int m = m0 + w*16 + quad*4 + r;
    if (m >= NN) continue;
    #pragma unroll
    for (int t = 0; t < 8; ++t){
      int col = t*16 + l15;
      unsigned short o = f2bf(acc2[t][r]);
      if (col < 64) fC[(size_t)m*GD + col] = o;
      else          fD[(size_t)m*GD + col - 64] = o;
    }
  }
}

// ------- edge aggregation, layer 1 (dim 128, 2 ch/lane, 4 nodes/block, bf16, ILP8) ----
__global__ __launch_bounds__(256)
void k_edge1(const unsigned short* __restrict__ A, const unsigned short* __restrict__ Bm,
             const float* __restrict__ b1, const int* __restrict__ offs,
             const int* __restrict__ cnt, const int* __restrict__ ssrc,
             unsigned short* __restrict__ S)
{
  int v = blockIdx.x*4 + (threadIdx.x >> 6);
  int c = threadIdx.x & 63;  // channels 2c, 2c+1
  int beg = offs[v], n = cnt[v];
  float sx = 0.f, sy = 0.f;
  if (n > 0){
    ushort2 a2 = *reinterpret_cast<const ushort2*>(&A[(size_t)v*GH + 2*c]);
    float2 bb = *reinterpret_cast<const float2*>(&b1[2*c]);
    float ax = bf2f(a2.x) + bb.x, ay = bf2f(a2.y) + bb.y;
    for (int i = 0; i < n; i += 8){
      int ss[8];
      #pragma unroll
      for (int j = 0; j < 8; ++j)
        ss[j] = (i + j < n) ? ssrc[beg + i + j] : ssrc[beg];
      ushort2 bv[8];
      #pragma unroll
      for (int j = 0; j < 8; ++j)
        bv[j] = *reinterpret_cast<const ushort2*>(&Bm[(size_t)ss[j]*GH + 2*c]);
      #pragma unroll
      for (int j = 0; j < 8; ++j){
        float live = (i + j < n) ? 1.f : 0.f;
        sx += live * fmaxf(ax + bf2f(bv[j].x), 0.f);
        sy += live * fmaxf(ay + bf2f(bv[j].y), 0.f);
      }
    }
  }
  ushort2 o; o.x = f2bf(sx); o.y = f2bf(sy);
  *reinterpret_cast<ushort2*>(&S[(size_t)v*GH + 2*c]) = o;
}

// ------- edge aggregation, layer 2 (dim 64, 1 ch/lane, 4 nodes/block, bf16, ILP8) -----
__global__ __launch_bounds__(256)
void k_edge2(const unsigned short* __restrict__ C, const unsigned short* __restrict__ D,
             const float* __restrict__ b1, const int* __restrict__ offs,
             const int* __restrict__ cnt, const int* __restrict__ ssrc,
             unsigned short* __restrict__ S2)
{
  int v = blockIdx.x*4 + (threadIdx.x >> 6);
  int c = threadIdx.x & 63;
  int beg = offs[v], n = cnt[v];
  float s = 0.f;
  if (n > 0){
    float a = bf2f(C[(size_t)v*GD + c]) + b1[c];
    for (int i = 0; i < n; i += 8){
      int ss[8];
      #pragma unroll
      for (int j = 0; j < 8; ++j)
        ss[j] = (i + j < n) ? ssrc[beg + i + j] : ssrc[beg];
      float dv[8];
      #pragma unroll
      for (int j = 0; j < 8; ++j)
        dv[j] = bf2f(D[(size_t)ss[j]*GD + c]);
      #pragma unroll
      for (int j = 0; j < 8; ++j){
        float live = (i + j < n) ? 1.f : 0.f;
        s += live * fmaxf(a + dv[j], 0.f);
      }
    }
  }
  S2[(size_t)v*GD + c] = f2bf(s);
}

// ---------------- actor head: one block per batch row (divide fused here) -----
__global__ __launch_bounds__(256)
void k_head(const float* __restrict__ state, const float* __restrict__ gsum,
            const int* __restrict__ nb,
            const float* __restrict__ fc1w, const float* __restrict__ fc1b,
            const float* __restrict__ fc2w, const float* __restrict__ fc2b,
            const float* __restrict__ mw, const float* __restrict__ mb,
            const float* __restrict__ lw, const float* __restrict__ lb,
            float* __restrict__ out)
{
  int b = blockIdx.x, t = threadIdx.x;
  __shared__ float z[SD + GD];
  __shared__ float h1[HID];
  __shared__ float h2[HID];
  __shared__ int bounds[2];
  if (t < 2){
    int target = b + t;
    int lo = 0, hi = NN;
    while (lo < hi){ int mid = (lo + hi) >> 1; if (nb[mid] < target) lo = mid + 1; else hi = mid; }
    bounds[t] = lo;
  }
  if (t < SD) z[t] = state[b*SD + t];
  __syncthreads();
  if (t >= SD && t < SD + GD){
    float n = (float)(bounds[1] - bounds[0]);
    z[t] = gsum[b*GD + (t - SD)] / fmaxf(n, 1.f);
  }
  __syncthreads();
  float acc = fc1b[t];
  for (int k = 0; k < SD + GD; ++k) acc = fmaf(z[k], fc1w[k*HID + t], acc);
  h1[t] = fmaxf(acc, 0.f);
  __syncthreads();
  acc = fc2b[t];
  for (int k = 0; k < HID; ++k) acc = fmaf(h1[k], fc2w[k*HID + t], acc);
  h2[t] = fmaxf(acc, 0.f);
  __syncthreads();
  if (t < AD){
    float m = mb[t];
    for (int k = 0; k < HID; ++k) m = fmaf(h2[k], mw[k*AD + t], m);
    out[b*AD + t] = m;
  } else if (t < 2*AD){
    int j = t - AD;
    float l = lb[j];
    for (int k = 0; k < HID; ++k) l = fmaf(h2[k], lw[k*AD + j], l);
    out[NB*AD + b*AD + j] = fminf(fmaxf(l, -20.f), 2.f);
  }
}

extern "C" void kernel_launch(void* const* d_in, const int* in_sizes, int n_in,
                              void* d_out, int out_size, void* d_ws, size_t ws_size,
                              hipStream_t stream)
{
  const float* state = (const float*)d_in[0];
  const float* x     = (const float*)d_in[1];
  const int*   eidx  = (const int*)  d_in[2];
  const int*   nb    = (const int*)  d_in[3];
  const float* g1w1  = (const float*)d_in[4];
  const float* g1b1  = (const float*)d_in[5];
  const float* g1w2  = (const float*)d_in[6];
  const float* g1b2  = (const float*)d_in[7];
  const float* g2w1  = (const float*)d_in[8];
  const float* g2b1  = (const float*)d_in[9];
  const float* g2w2  = (const float*)d_in[10];
  const float* g2b2  = (const float*)d_in[11];
  const float* fc1w  = (const float*)d_in[12];
  const float* fc1b  = (const float*)d_in[13];
  const float* fc2w  = (const float*)d_in[14];
  const float* fc2b  = (const float*)d_in[15];
  const float* mw    = (const float*)d_in[16];
  const float* mb    = (const float*)d_in[17];
  const float* lw    = (const float*)d_in[18];
  const float* lb    = (const float*)d_in[19];

  const int* e_src = eidx;        // edge_index[0]
  const int* e_dst = eidx + NE;   // edge_index[1]

  char* p = (char*)d_ws;
  auto alloc = [&](size_t bytes){ char* r = p; p += align256(bytes); return r; };
  int*   cnt    = (int*)  alloc((size_t)NN*4);
  int*   offs   = (int*)  alloc((size_t)NN*4);
  int*   rank   = (int*)  alloc((size_t)NE*4);
  int*   ssrc   = (int*)  alloc((size_t)NE*4);
  int*   bsum   = (int*)  alloc((size_t)SCB*4);
  int*   boff   = (int*)  alloc((size_t)SCB*4);
  float* gsum   = (float*)alloc((size_t)NB*GD*4);
  unsigned short* xb = (unsigned short*)alloc((size_t)NN*SD*2);   // bf16 x
  unsigned short* wb = (unsigned short*)alloc((size_t)53248*2);   // bf16 weights
  unsigned short* fA = (unsigned short*)alloc((size_t)NN*GH*2);   // bf16 [NN,128]
  unsigned short* fB = (unsigned short*)alloc((size_t)NN*GH*2);   // bf16 [NN,128]
  unsigned short* fS = (unsigned short*)alloc((size_t)NN*GH*2);   // bf16 [NN,128]
  // overlays (lifetimes disjoint):
  unsigned short* fC = fA;                          // bf16 [NN,64]
  unsigned short* fD = fA + (size_t)NN*GD;          // bf16 [NN,64]
  unsigned short* fS2= fB;                          // bf16 [NN,64]

  unsigned short* wb1 = wb;            // g1w1 [128,128]
  unsigned short* wb2 = wb + 16384;    // g1w2 [128,128]
  unsigned short* wb3 = wb + 32768;    // g2w1 [256,64]
  unsigned short* wb4 = wb + 49152;    // g2w2 [64,64]

  hipMemsetAsync(cnt, 0, (size_t)NN*4, stream);
  hipMemsetAsync(gsum, 0, (size_t)NB*GD*4, stream);

  dim3 b256(256);
  const int EB = (NE + 2047)/2048;   // 391
  k_prep  <<<dim3(800), b256, 0, stream>>>(x, g1w1, g1w2, g2w1, g2w2, xb, wb);
  k_hist  <<<dim3(EB), b256, 0, stream>>>(e_dst, cnt, rank);
  k_scan_a<<<dim3(SCB), b256, 0, stream>>>(cnt, bsum);
  k_scan_b<<<dim3(1),   b256, 0, stream>>>(bsum, boff);
  k_scan_c<<<dim3(SCB), b256, 0, stream>>>(cnt, boff, offs);
  k_place <<<dim3(EB), b256, 0, stream>>>(e_src, e_dst, offs, rank, ssrc);

  const int MB = (NN + 63)/64;  // 782
  // Layer 1: fA = x @ w1[0:64,:], fB = x @ w1[64:128,:]  (bf16, z-fused)
  k_mgemm<1,0><<<dim3(MB,2,2), b256, 0, stream>>>(xb, wb1, fA, wb1 + 64*GH, fB,
                                                  NN, 64, GH, GH, nullptr, nullptr, 0,
                                                  nullptr, nullptr);
  k_edge1<<<dim3(NN/4), b256, 0, stream>>>(fA, fB, g1b1, offs, cnt, ssrc, fS);
  // fused: h = relu(mean(fS@w2)); fC|fD = h @ g2w1 halves
  k_mlp2<<<dim3(MB), b256, 0, stream>>>(fS, wb2, wb3, cnt, g1b2, fC, fD);
  k_edge2<<<dim3(NN/4), b256, 0, stream>>>(fC, fD, g2b1, offs, cnt, ssrc, fS2);
  // h2 = mean(fS2@w4) with graph-sum epilogue directly into gsum
  k_mgemm<0,1><<<dim3(MB,1,1), b256, 0, stream>>>(fS2, wb4, nullptr, wb4, nullptr,
                                                  NN, 64, GD, GD, cnt, g2b2, 0,
                                                  nb, gsum);
  k_head<<<dim3(NB), b256, 0, stream>>>(state, gsum, nb, fc1w, fc1b, fc2w, fc2b,
                                        mw, mb, lw, lb, (float*)d_out);
}